// Round 1
// baseline (574.365 us; speedup 1.0000x reference)
//
#include <hip/hip_runtime.h>

#define N_ANCH 25200
#define NCLS   80
#define ROW    85
#define NIMG   16
#define KMAX   1024
#define NBINS  4096
#define CAND_CAP 4096
#define CHUNKS_PER_IMG 394   // ceil(25200/64)

typedef unsigned long long u64;
typedef unsigned int u32;

// ---------------- ws layout (bytes) ----------------
#define OFF_KEYS 0ull                      // 16*25200*8 = 3,225,600
#define OFF_HIST 3225600ull                // 16*4096*4  =   262,144
#define OFF_TBIN 3487744ull                // 16*4 = 64
#define OFF_CCNT 3487808ull                // 16*4 = 64
#define OFF_SUMS 3487872ull                // 8*4 = 32
#define OFF_CNTS 3487904ull                // 8*4 = 32
#define OFF_CAND 3487936ull                // 16*4096*8 = 524,288
#define OFF_SEL  4012224ull                // 16*1024*8 = 131,072
#define OFF_BOX  4143296ull                // 16*1024*16 = 262,144
#define OFF_CLS  4405440ull                // 16*1024*4 = 65,536
#define OFF_VAL  4470976ull                // 16*1024*4 = 65,536
#define OFF_KEEP 4536512ull                // 16*1024*4 = 65,536
#define WS_NEED  4602048ull
#define ZERO_BYTES (262144ull + 64 + 64 + 32 + 32)   // hist..cnts contiguous

__device__ __forceinline__ int key_bin(u64 key) {
    u32 hi = (u32)(key >> 32);
    if (hi == 0u) return 0;
    float conf = __uint_as_float(hi - 0x40000000u);
    int b = 1 + (int)(conf * 4093.0f);
    return b > 4094 ? 4094 : b;
}

// K1: per-entry conf/cls/validity -> 64-bit sort key. Wave-staged coalesced loads.
__global__ __launch_bounds__(128) void k_score(const float* __restrict__ clean,
                                               const float* __restrict__ patch,
                                               u64* __restrict__ keys)
{
    __shared__ float lds[2][5440];   // 2 waves * 64 entries * 85 floats
    const int wv   = threadIdx.x >> 6;
    const int lane = threadIdx.x & 63;
    const int wave_id = blockIdx.x * 2 + wv;        // grid sized exactly: 16*394/2 blocks
    const int b     = wave_id / CHUNKS_PER_IMG;
    const int chunk = wave_id - b * CHUNKS_PER_IMG;
    const float* src = (b < 8) ? (clean + (size_t)b * N_ANCH * ROW)
                               : (patch + (size_t)(b - 8) * N_ANCH * ROW);
    const int base = chunk * 64;
    const int n_e  = min(64, N_ANCH - base);
    const int n4   = (n_e * ROW) >> 2;              // rows*85 divisible by 4 (64*85, 48*85)
    const float4* s4 = (const float4*)(src + (size_t)base * ROW);
    float4* l4 = (float4*)(&lds[wv][0]);
    for (int t = lane; t < n4; t += 64) l4[t] = s4[t];
    __syncthreads();
    if (lane < n_e) {
        const float* p = &lds[wv][lane * ROW];
        const float obj = p[4];
        float best = -1.0f; int bc = 0;
        #pragma unroll 8
        for (int d = 0; d < NCLS; ++d) {
            float s = p[5 + d] * obj;
            if (s > best) { best = s; bc = d; }
        }
        const float th = (b < 8) ? 0.25f : 0.001f;
        const bool valid = (obj > th) && (best > th);
        const u32 hi = valid ? (__float_as_uint(best) + 0x40000000u) : 0u;
        const u32 nbar = 32767u - (u32)(base + lane);
        keys[(size_t)b * N_ANCH + base + lane] =
            ((u64)hi << 32) | ((u64)nbar << 8) | (u64)(u32)bc;
    }
}

// K2: per-image histogram of conf bins
__global__ __launch_bounds__(256) void k_hist(const u64* __restrict__ keys,
                                              int* __restrict__ hist)
{
    __shared__ int h[NBINS];
    const int b = blockIdx.x;
    for (int i = threadIdx.x; i < NBINS; i += 256) h[i] = 0;
    __syncthreads();
    const int start = blockIdx.y * 1575;
    const u64* kp = keys + (size_t)b * N_ANCH;
    for (int i = start + threadIdx.x; i < start + 1575; i += 256)
        atomicAdd(&h[key_bin(kp[i])], 1);
    __syncthreads();
    for (int i = threadIdx.x; i < NBINS; i += 256)
        if (h[i]) atomicAdd(&hist[b * NBINS + i], h[i]);
}

// K3: per-image suffix-scan over bins -> threshold bin so that count(bin >= T) >= K
__global__ __launch_bounds__(1024) void k_thresh(const int* __restrict__ hist,
                                                 int* __restrict__ tbin)
{
    __shared__ int arr[1024];
    const int b = blockIdx.x;
    const int t = threadIdx.x;
    int hh[4];
    hh[0] = hist[b * NBINS + 4 * t + 0];
    hh[1] = hist[b * NBINS + 4 * t + 1];
    hh[2] = hist[b * NBINS + 4 * t + 2];
    hh[3] = hist[b * NBINS + 4 * t + 3];
    const int r = hh[0] + hh[1] + hh[2] + hh[3];
    arr[t] = r;
    __syncthreads();
    for (int off = 1; off < 1024; off <<= 1) {
        int v = (t + off < 1024) ? arr[t + off] : 0;
        __syncthreads();
        arr[t] += v;
        __syncthreads();
    }
    const int K = (b < 8) ? 256 : 1024;
    int cb = arr[t] - r;                 // count of bins strictly above this 4-group
    for (int d = 3; d >= 0; --d) {
        int ca = cb + hh[d];
        if (cb < K && ca >= K) tbin[b] = 4 * t + d;
        cb = ca;
    }
}

// K4: compact candidates with bin >= T
__global__ __launch_bounds__(256) void k_compact(const u64* __restrict__ keys,
                                                 const int* __restrict__ tbin,
                                                 int* __restrict__ ccnt,
                                                 u64* __restrict__ cand)
{
    const int b = blockIdx.x;
    const int T = tbin[b];
    const u64* kp = keys + (size_t)b * N_ANCH;
    const int start = blockIdx.y * 1575;
    for (int i = start + threadIdx.x; i < start + 1575; i += 256) {
        u64 key = kp[i];
        if (key_bin(key) >= T) {
            int pos = atomicAdd(&ccnt[b], 1);
            if (pos < CAND_CAP) cand[(size_t)b * CAND_CAP + pos] = key;
        }
    }
}

// K5: per-image bitonic sort (descending) of candidates, emit top-K keys
__global__ __launch_bounds__(1024) void k_sort(const u64* __restrict__ cand,
                                               const int* __restrict__ ccnt,
                                               u64* __restrict__ sel)
{
    __shared__ u64 sk[CAND_CAP];   // 32 KB
    const int b = blockIdx.x;
    const int C = min(ccnt[b], CAND_CAP);
    const int t = threadIdx.x;
    #pragma unroll
    for (int p = 0; p < CAND_CAP / 1024; ++p) {
        int i = p * 1024 + t;
        sk[i] = (i < C) ? cand[(size_t)b * CAND_CAP + i] : 0ull;
    }
    __syncthreads();
    for (int k = 2; k <= CAND_CAP; k <<= 1) {
        for (int j = k >> 1; j > 0; j >>= 1) {
            #pragma unroll
            for (int p = 0; p < CAND_CAP / 1024; ++p) {
                int i = p * 1024 + t;
                int ixj = i ^ j;
                if (ixj > i) {
                    u64 a = sk[i], c = sk[ixj];
                    bool descSeg = ((i & k) == 0);
                    bool sw = descSeg ? (a < c) : (a > c);
                    if (sw) { sk[i] = c; sk[ixj] = a; }
                }
            }
            __syncthreads();
        }
    }
    const int K = (b < 8) ? 256 : 1024;
    if (t < K) sel[b * KMAX + t] = sk[t];
}

// K6: decode keys, gather boxes (xywh->xyxy), cls, validity
__global__ __launch_bounds__(1024) void k_gather(const float* __restrict__ clean,
                                                 const float* __restrict__ patch,
                                                 const u64* __restrict__ sel,
                                                 float4* __restrict__ boxes,
                                                 int* __restrict__ cls,
                                                 int* __restrict__ vflag)
{
    const int b = blockIdx.x;
    const int t = threadIdx.x;
    const int K = (b < 8) ? 256 : 1024;
    if (t >= K) return;
    const u64 key = sel[b * KMAX + t];
    const u32 hi = (u32)(key >> 32);
    const int n = 32767 - (int)((key >> 8) & 0x7FFFu);
    const int c = (int)(key & 0x7Fu);
    const float* src = ((b < 8) ? (clean + (size_t)b * N_ANCH * ROW)
                                : (patch + (size_t)(b - 8) * N_ANCH * ROW)) + (size_t)n * ROW;
    const float x = src[0], y = src[1], w = src[2], h = src[3];
    boxes[b * KMAX + t] = make_float4(x - w * 0.5f, y - h * 0.5f, x + w * 0.5f, y + h * 0.5f);
    cls[b * KMAX + t] = c;
    vflag[b * KMAX + t] = (hi != 0u) ? 1 : 0;
}

// K7: greedy NMS per image (class-offset boxes), serialized with one barrier/iter
__global__ __launch_bounds__(1024) void k_nms(const float4* __restrict__ boxes,
                                              const int* __restrict__ cls,
                                              const int* __restrict__ vflag,
                                              int* __restrict__ keep)
{
    __shared__ float4 bx[KMAX];
    __shared__ int remv[KMAX];
    const int b = blockIdx.x;
    const int t = threadIdx.x;
    const int K = (b < 8) ? 256 : 1024;
    if (t < K) {
        float4 v = boxes[b * KMAX + t];
        float off = (float)cls[b * KMAX + t] * 4096.0f;
        v.x += off; v.y += off; v.z += off; v.w += off;
        bx[t] = v;
        remv[t] = vflag[b * KMAX + t] ? 0 : 1;
    }
    __syncthreads();
    float4 mybox = make_float4(0.f, 0.f, 0.f, 0.f);
    float myarea = 0.f;
    if (t < K) { mybox = bx[t]; myarea = (mybox.z - mybox.x) * (mybox.w - mybox.y); }
    for (int i = 0; i < K - 1; ++i) {
        __syncthreads();
        if (remv[i]) continue;               // uniform (LDS broadcast read)
        float4 bi = bx[i];
        if (t > i && t < K) {
            float ax = fmaxf(bi.x, mybox.x), ay = fmaxf(bi.y, mybox.y);
            float bx2 = fminf(bi.z, mybox.z), by2 = fminf(bi.w, mybox.w);
            float iw = fmaxf(bx2 - ax, 0.f), ih = fmaxf(by2 - ay, 0.f);
            float inter = iw * ih;
            float ai = (bi.z - bi.x) * (bi.w - bi.y);
            float iou = inter / (ai + myarea - inter);
            if (iou > 0.45f) remv[t] = 1;
        }
    }
    __syncthreads();
    if (t < K) keep[b * KMAX + t] = (remv[t] == 0) ? 1 : 0;
}

// K8: per clean image: tm_j = max IoU over kept same-class patch boxes; reduce
__global__ __launch_bounds__(256) void k_match(const float4* __restrict__ boxes,
                                               const int* __restrict__ cls,
                                               const int* __restrict__ keep,
                                               float* __restrict__ sums,
                                               float* __restrict__ cnts)
{
    __shared__ float4 pb[KMAX];
    __shared__ int pcls[KMAX];
    __shared__ int pk[KMAX];
    __shared__ float red[8];
    const int c = blockIdx.x;        // clean image 0..7
    const int bp = 8 + c;
    const int t = threadIdx.x;
    for (int i = t; i < KMAX; i += 256) {
        pb[i]   = boxes[bp * KMAX + i];
        pcls[i] = cls[bp * KMAX + i];
        pk[i]   = keep[bp * KMAX + i];
    }
    __syncthreads();
    const float4 bc = boxes[c * KMAX + t];
    const int cc = cls[c * KMAX + t];
    const int kc = keep[c * KMAX + t];
    const float area_c = (bc.z - bc.x) * (bc.w - bc.y);
    float tm = 0.f;
    for (int i = 0; i < KMAX; ++i) {
        if (pk[i] && pcls[i] == cc) {
            float4 bi = pb[i];
            float ax = fmaxf(bi.x, bc.x), ay = fmaxf(bi.y, bc.y);
            float bx2 = fminf(bi.z, bc.z), by2 = fminf(bi.w, bc.w);
            float iw = fmaxf(bx2 - ax, 0.f), ih = fmaxf(by2 - ay, 0.f);
            float inter = iw * ih;
            float ai = (bi.z - bi.x) * (bi.w - bi.y);
            float iou = inter / (ai + area_c - inter);
            tm = fmaxf(tm, iou);
        }
    }
    float val = kc ? tm : 0.f;
    float cv  = kc ? 1.f : 0.f;
    for (int off = 32; off > 0; off >>= 1) {
        val += __shfl_down(val, off);
        cv  += __shfl_down(cv, off);
    }
    const int wv = t >> 6, lane = t & 63;
    if (lane == 0) { red[wv] = val; red[4 + wv] = cv; }
    __syncthreads();
    if (t == 0) {
        sums[c] = red[0] + red[1] + red[2] + red[3];
        cnts[c] = red[4] + red[5] + red[6] + red[7];
    }
}

// K9: scalar epilogue
__global__ void k_final(const float* __restrict__ sums,
                        const float* __restrict__ cnts,
                        float* __restrict__ out)
{
    if (threadIdx.x == 0 && blockIdx.x == 0) {
        float total = 0.f, cnt = 0.f;
        for (int c = 0; c < 8; ++c) { total += sums[c]; cnt += cnts[c]; }
        out[0] = (cnt > 0.f) ? (1.0f - total / fmaxf(cnt, 1.0f)) : 1.0f;
    }
}

extern "C" void kernel_launch(void* const* d_in, const int* in_sizes, int n_in,
                              void* d_out, int out_size, void* d_ws, size_t ws_size,
                              hipStream_t stream)
{
    if (ws_size < WS_NEED) return;
    const float* clean = (const float*)d_in[0];
    const float* patch = (const float*)d_in[1];
    float* out = (float*)d_out;
    char* ws = (char*)d_ws;

    u64*    keys = (u64*)(ws + OFF_KEYS);
    int*    hist = (int*)(ws + OFF_HIST);
    int*    tbin = (int*)(ws + OFF_TBIN);
    int*    ccnt = (int*)(ws + OFF_CCNT);
    float*  sums = (float*)(ws + OFF_SUMS);
    float*  cnts = (float*)(ws + OFF_CNTS);
    u64*    cand = (u64*)(ws + OFF_CAND);
    u64*    sel  = (u64*)(ws + OFF_SEL);
    float4* boxes = (float4*)(ws + OFF_BOX);
    int*    cls  = (int*)(ws + OFF_CLS);
    int*    vflag = (int*)(ws + OFF_VAL);
    int*    keep = (int*)(ws + OFF_KEEP);

    hipMemsetAsync(ws + OFF_HIST, 0, ZERO_BYTES, stream);

    k_score<<<(NIMG * CHUNKS_PER_IMG) / 2, 128, 0, stream>>>(clean, patch, keys);
    k_hist<<<dim3(NIMG, 16), 256, 0, stream>>>(keys, hist);
    k_thresh<<<NIMG, 1024, 0, stream>>>(hist, tbin);
    k_compact<<<dim3(NIMG, 16), 256, 0, stream>>>(keys, tbin, ccnt, cand);
    k_sort<<<NIMG, 1024, 0, stream>>>(cand, ccnt, sel);
    k_gather<<<NIMG, 1024, 0, stream>>>(clean, patch, sel, boxes, cls, vflag);
    k_nms<<<NIMG, 1024, 0, stream>>>(boxes, cls, vflag, keep);
    k_match<<<8, 256, 0, stream>>>(boxes, cls, keep, sums, cnts);
    k_final<<<1, 64, 0, stream>>>(sums, cnts, out);
}

// Round 2
// 426.759 us; speedup vs baseline: 1.3459x; 1.3459x over previous
//
#include <hip/hip_runtime.h>

#define N_ANCH 25200
#define NCLS   80
#define ROW    85
#define NIMG   16
#define KMAX   1024
#define NBINS  4096
#define CAND_CAP 4096
#define CHUNKS_PER_IMG 394   // ceil(25200/64)

typedef unsigned long long u64;
typedef unsigned int u32;

// ---------------- ws layout (bytes) ----------------
#define OFF_KEYS 0ull                      // 16*25200*8 = 3,225,600 ; reused as NMS mask (2 MB) after k_sort
#define OFF_HIST 3225600ull                // 16*4096*4  =   262,144
#define OFF_TBIN 3487744ull                // 16*4 = 64
#define OFF_CCNT 3487808ull                // 16*4 = 64
#define OFF_SUMS 3487872ull                // 8*4 = 32
#define OFF_CNTS 3487904ull                // 8*4 = 32
#define OFF_CAND 3487936ull                // 16*4096*8 = 524,288
#define OFF_SEL  4012224ull                // 16*1024*8 = 131,072
#define OFF_BOX  4143296ull                // 16*1024*16 = 262,144
#define OFF_CLS  4405440ull                // 16*1024*4 = 65,536
#define OFF_RINIT 4470976ull               // 16*16*8 = 2,048 (initial removal bitmask)
#define OFF_KEEP 4536512ull                // 16*1024*4 = 65,536
#define WS_NEED  4602048ull
#define ZERO_BYTES (262144ull + 64 + 64 + 32 + 32)   // hist..cnts contiguous

__device__ __forceinline__ int key_bin(u64 key) {
    u32 hi = (u32)(key >> 32);
    if (hi == 0u) return 0;
    float conf = __uint_as_float(hi - 0x40000000u);
    int b = 1 + (int)(conf * 4093.0f);
    return b > 4094 ? 4094 : b;
}

__device__ __forceinline__ u64 shfl64(u64 v, int src) {
    int lo = __shfl((int)(u32)(v & 0xffffffffull), src, 64);
    int hi = __shfl((int)(u32)(v >> 32), src, 64);
    return ((u64)(u32)hi << 32) | (u64)(u32)lo;
}

// K1: per-entry conf/cls/validity -> 64-bit sort key. Wave-staged coalesced loads.
__global__ __launch_bounds__(128) void k_score(const float* __restrict__ clean,
                                               const float* __restrict__ patch,
                                               u64* __restrict__ keys)
{
    __shared__ float lds[2][5440];   // 2 waves * 64 entries * 85 floats
    const int wv   = threadIdx.x >> 6;
    const int lane = threadIdx.x & 63;
    const int wave_id = blockIdx.x * 2 + wv;
    const int b     = wave_id / CHUNKS_PER_IMG;
    const int chunk = wave_id - b * CHUNKS_PER_IMG;
    const float* src = (b < 8) ? (clean + (size_t)b * N_ANCH * ROW)
                               : (patch + (size_t)(b - 8) * N_ANCH * ROW);
    const int base = chunk * 64;
    const int n_e  = min(64, N_ANCH - base);
    const int n4   = (n_e * ROW) >> 2;
    const float4* s4 = (const float4*)(src + (size_t)base * ROW);
    float4* l4 = (float4*)(&lds[wv][0]);
    for (int t = lane; t < n4; t += 64) l4[t] = s4[t];
    __syncthreads();
    if (lane < n_e) {
        const float* p = &lds[wv][lane * ROW];
        const float obj = p[4];
        float best = -1.0f; int bc = 0;
        #pragma unroll 8
        for (int d = 0; d < NCLS; ++d) {
            float s = p[5 + d] * obj;
            if (s > best) { best = s; bc = d; }
        }
        const float th = (b < 8) ? 0.25f : 0.001f;
        const bool valid = (obj > th) && (best > th);
        const u32 hi = valid ? (__float_as_uint(best) + 0x40000000u) : 0u;
        const u32 nbar = 32767u - (u32)(base + lane);
        keys[(size_t)b * N_ANCH + base + lane] =
            ((u64)hi << 32) | ((u64)nbar << 8) | (u64)(u32)bc;
    }
}

// K2: per-image histogram of conf bins
__global__ __launch_bounds__(256) void k_hist(const u64* __restrict__ keys,
                                              int* __restrict__ hist)
{
    __shared__ int h[NBINS];
    const int b = blockIdx.x;
    for (int i = threadIdx.x; i < NBINS; i += 256) h[i] = 0;
    __syncthreads();
    const int start = blockIdx.y * 1575;
    const u64* kp = keys + (size_t)b * N_ANCH;
    for (int i = start + threadIdx.x; i < start + 1575; i += 256)
        atomicAdd(&h[key_bin(kp[i])], 1);
    __syncthreads();
    for (int i = threadIdx.x; i < NBINS; i += 256)
        if (h[i]) atomicAdd(&hist[b * NBINS + i], h[i]);
}

// K3: per-image suffix-scan over bins -> threshold bin
__global__ __launch_bounds__(1024) void k_thresh(const int* __restrict__ hist,
                                                 int* __restrict__ tbin)
{
    __shared__ int arr[1024];
    const int b = blockIdx.x;
    const int t = threadIdx.x;
    int hh[4];
    hh[0] = hist[b * NBINS + 4 * t + 0];
    hh[1] = hist[b * NBINS + 4 * t + 1];
    hh[2] = hist[b * NBINS + 4 * t + 2];
    hh[3] = hist[b * NBINS + 4 * t + 3];
    const int r = hh[0] + hh[1] + hh[2] + hh[3];
    arr[t] = r;
    __syncthreads();
    for (int off = 1; off < 1024; off <<= 1) {
        int v = (t + off < 1024) ? arr[t + off] : 0;
        __syncthreads();
        arr[t] += v;
        __syncthreads();
    }
    const int K = (b < 8) ? 256 : 1024;
    int cb = arr[t] - r;
    for (int d = 3; d >= 0; --d) {
        int ca = cb + hh[d];
        if (cb < K && ca >= K) tbin[b] = 4 * t + d;
        cb = ca;
    }
}

// K4: compact candidates with bin >= T
__global__ __launch_bounds__(256) void k_compact(const u64* __restrict__ keys,
                                                 const int* __restrict__ tbin,
                                                 int* __restrict__ ccnt,
                                                 u64* __restrict__ cand)
{
    const int b = blockIdx.x;
    const int T = tbin[b];
    const u64* kp = keys + (size_t)b * N_ANCH;
    const int start = blockIdx.y * 1575;
    for (int i = start + threadIdx.x; i < start + 1575; i += 256) {
        u64 key = kp[i];
        if (key_bin(key) >= T) {
            int pos = atomicAdd(&ccnt[b], 1);
            if (pos < CAND_CAP) cand[(size_t)b * CAND_CAP + pos] = key;
        }
    }
}

// K5: per-image bitonic sort (descending) of candidates, emit top-K keys
__global__ __launch_bounds__(1024) void k_sort(const u64* __restrict__ cand,
                                               const int* __restrict__ ccnt,
                                               u64* __restrict__ sel)
{
    __shared__ u64 sk[CAND_CAP];   // 32 KB
    const int b = blockIdx.x;
    const int C = min(ccnt[b], CAND_CAP);
    const int t = threadIdx.x;
    #pragma unroll
    for (int p = 0; p < CAND_CAP / 1024; ++p) {
        int i = p * 1024 + t;
        sk[i] = (i < C) ? cand[(size_t)b * CAND_CAP + i] : 0ull;
    }
    __syncthreads();
    for (int k = 2; k <= CAND_CAP; k <<= 1) {
        for (int j = k >> 1; j > 0; j >>= 1) {
            #pragma unroll
            for (int p = 0; p < CAND_CAP / 1024; ++p) {
                int i = p * 1024 + t;
                int ixj = i ^ j;
                if (ixj > i) {
                    u64 a = sk[i], c = sk[ixj];
                    bool descSeg = ((i & k) == 0);
                    bool sw = descSeg ? (a < c) : (a > c);
                    if (sw) { sk[i] = c; sk[ixj] = a; }
                }
            }
            __syncthreads();
        }
    }
    const int K = (b < 8) ? 256 : 1024;
    if (t < K) sel[b * KMAX + t] = sk[t];
}

// K6: decode keys, gather boxes (xywh->xyxy), cls; ballot initial removal mask
__global__ __launch_bounds__(1024) void k_gather(const float* __restrict__ clean,
                                                 const float* __restrict__ patch,
                                                 const u64* __restrict__ sel,
                                                 float4* __restrict__ boxes,
                                                 int* __restrict__ cls,
                                                 u64* __restrict__ rinit)
{
    const int b = blockIdx.x;
    const int t = threadIdx.x;
    const int K = (b < 8) ? 256 : 1024;
    const u64 key = (t < K) ? sel[b * KMAX + t] : 0ull;
    const u32 hi = (u32)(key >> 32);
    const bool valid = (t < K) && (hi != 0u);
    u64 bal = __ballot(valid);
    if ((t & 63) == 0) rinit[b * 16 + (t >> 6)] = ~bal;
    if (t >= K) return;
    const int n = 32767 - (int)((key >> 8) & 0x7FFFu);
    const int c = (int)(key & 0x7Fu);
    const float* src = ((b < 8) ? (clean + (size_t)b * N_ANCH * ROW)
                                : (patch + (size_t)(b - 8) * N_ANCH * ROW)) + (size_t)n * ROW;
    const float x = src[0], y = src[1], w = src[2], h = src[3];
    boxes[b * KMAX + t] = make_float4(x - w * 0.5f, y - h * 0.5f, x + w * 0.5f, y + h * 0.5f);
    cls[b * KMAX + t] = c;
}

// K7a: parallel suppression-mask build. Wave = one 64-bit word column across 64 rows.
__global__ __launch_bounds__(1024) void k_nms_mask(const float4* __restrict__ boxes,
                                                   const int* __restrict__ cls,
                                                   u64* __restrict__ mask)
{
    __shared__ float4 bx[KMAX];
    __shared__ float ar[KMAX];
    const int b = blockIdx.x;
    const int K = (b < 8) ? 256 : 1024;
    const int row0 = blockIdx.y * 64;
    if (row0 >= K) return;                  // block-uniform
    const int t = threadIdx.x;
    for (int i = t; i < K; i += 1024) {
        float4 v = boxes[b * KMAX + i];
        float off = (float)cls[b * KMAX + i] * 4096.0f;
        v.x += off; v.y += off; v.z += off; v.w += off;
        bx[i] = v;
        ar[i] = (v.z - v.x) * (v.w - v.y);
    }
    __syncthreads();
    const int w   = t >> 6;                 // word column (wave-uniform)
    const int row = row0 + (t & 63);        // lane-distinct row
    u64* dst = mask + ((size_t)b * KMAX + row) * 16 + w;
    if (((w << 6) + 63) <= row0 && row0 > 0) { *dst = 0ull; return; }   // all j <= min row: zero word
    const float4 bi = bx[row];
    const float ai = ar[row];
    const int jbase = w << 6;
    u64 m = 0;
    #pragma unroll 8
    for (int k = 0; k < 64; ++k) {
        const int j = jbase + k;            // wave-uniform -> LDS broadcast
        const float4 bj = bx[j];
        const float ax = fmaxf(bi.x, bj.x), ay = fmaxf(bi.y, bj.y);
        const float bx2 = fminf(bi.z, bj.z), by2 = fminf(bi.w, bj.w);
        const float iw = fmaxf(bx2 - ax, 0.f), ih = fmaxf(by2 - ay, 0.f);
        const float inter = iw * ih;
        const float iou = inter / (ai + ar[j] - inter);
        if (j > row && iou > 0.45f) m |= (1ull << k);
    }
    *dst = m;
}

// K7b: serial scan, one wave per image, zero barriers. Lanes 0..15 own removal words.
__global__ __launch_bounds__(64) void k_nms_scan(const u64* __restrict__ mask,
                                                 const u64* __restrict__ rinit,
                                                 int* __restrict__ keep)
{
    const int b = blockIdx.x;
    const int K = (b < 8) ? 256 : 1024;
    const int W = K >> 6;
    const int lane = threadIdx.x;
    const int wl = lane & 15;               // lanes 16+ mirror words 0..15 (values unused)
    u64 w_remv = rinit[b * 16 + wl];
    const u64* mrow = mask + (size_t)b * KMAX * 16;
    #pragma unroll 2
    for (int i = 0; i < K; i += 4) {
        const u64* p = mrow + (size_t)i * 16 + wl;
        const u64 m0 = p[0], m1 = p[16], m2 = p[32], m3 = p[48];
        const int owner = i >> 6;
        const u64 ow  = shfl64(w_remv, owner);
        const u64 m0o = shfl64(m0, owner);
        const u64 m1o = shfl64(m1, owner);
        const u64 m2o = shfl64(m2, owner);
        const int b0 = i & 63;
        const bool k0 = !((ow >> b0) & 1);
        u64 acc = k0 ? m0o : 0ull;
        const bool k1 = !(((ow | acc) >> (b0 + 1)) & 1);
        if (k1) acc |= m1o;
        const bool k2 = !(((ow | acc) >> (b0 + 2)) & 1);
        if (k2) acc |= m2o;
        const bool k3 = !(((ow | acc) >> (b0 + 3)) & 1);
        w_remv |= (k0 ? m0 : 0ull) | (k1 ? m1 : 0ull) | (k2 ? m2 : 0ull) | (k3 ? m3 : 0ull);
    }
    if (lane < W) {
        for (int k = 0; k < 64; ++k)
            keep[b * KMAX + lane * 64 + k] = (int)(((w_remv >> k) & 1) ^ 1ull);
    }
}

// K8: per clean image: tm_j = max IoU over kept same-class patch boxes; reduce
__global__ __launch_bounds__(256) void k_match(const float4* __restrict__ boxes,
                                               const int* __restrict__ cls,
                                               const int* __restrict__ keep,
                                               float* __restrict__ sums,
                                               float* __restrict__ cnts)
{
    __shared__ float4 pb[KMAX];
    __shared__ int pcls[KMAX];
    __shared__ int pk[KMAX];
    __shared__ float red[8];
    const int c = blockIdx.x;
    const int bp = 8 + c;
    const int t = threadIdx.x;
    for (int i = t; i < KMAX; i += 256) {
        pb[i]   = boxes[bp * KMAX + i];
        pcls[i] = cls[bp * KMAX + i];
        pk[i]   = keep[bp * KMAX + i];
    }
    __syncthreads();
    const float4 bc = boxes[c * KMAX + t];
    const int cc = cls[c * KMAX + t];
    const int kc = keep[c * KMAX + t];
    const float area_c = (bc.z - bc.x) * (bc.w - bc.y);
    float tm = 0.f;
    for (int i = 0; i < KMAX; ++i) {
        if (pk[i] && pcls[i] == cc) {
            float4 bi = pb[i];
            float ax = fmaxf(bi.x, bc.x), ay = fmaxf(bi.y, bc.y);
            float bx2 = fminf(bi.z, bc.z), by2 = fminf(bi.w, bc.w);
            float iw = fmaxf(bx2 - ax, 0.f), ih = fmaxf(by2 - ay, 0.f);
            float inter = iw * ih;
            float ai = (bi.z - bi.x) * (bi.w - bi.y);
            float iou = inter / (ai + area_c - inter);
            tm = fmaxf(tm, iou);
        }
    }
    float val = kc ? tm : 0.f;
    float cv  = kc ? 1.f : 0.f;
    for (int off = 32; off > 0; off >>= 1) {
        val += __shfl_down(val, off);
        cv  += __shfl_down(cv, off);
    }
    const int wv = t >> 6, lane = t & 63;
    if (lane == 0) { red[wv] = val; red[4 + wv] = cv; }
    __syncthreads();
    if (t == 0) {
        sums[c] = red[0] + red[1] + red[2] + red[3];
        cnts[c] = red[4] + red[5] + red[6] + red[7];
    }
}

// K9: scalar epilogue
__global__ void k_final(const float* __restrict__ sums,
                        const float* __restrict__ cnts,
                        float* __restrict__ out)
{
    if (threadIdx.x == 0 && blockIdx.x == 0) {
        float total = 0.f, cnt = 0.f;
        for (int c = 0; c < 8; ++c) { total += sums[c]; cnt += cnts[c]; }
        out[0] = (cnt > 0.f) ? (1.0f - total / fmaxf(cnt, 1.0f)) : 1.0f;
    }
}

extern "C" void kernel_launch(void* const* d_in, const int* in_sizes, int n_in,
                              void* d_out, int out_size, void* d_ws, size_t ws_size,
                              hipStream_t stream)
{
    if (ws_size < WS_NEED) return;
    const float* clean = (const float*)d_in[0];
    const float* patch = (const float*)d_in[1];
    float* out = (float*)d_out;
    char* ws = (char*)d_ws;

    u64*    keys = (u64*)(ws + OFF_KEYS);
    u64*    mask = (u64*)(ws + OFF_KEYS);   // reuses keys region after k_sort
    int*    hist = (int*)(ws + OFF_HIST);
    int*    tbin = (int*)(ws + OFF_TBIN);
    int*    ccnt = (int*)(ws + OFF_CCNT);
    float*  sums = (float*)(ws + OFF_SUMS);
    float*  cnts = (float*)(ws + OFF_CNTS);
    u64*    cand = (u64*)(ws + OFF_CAND);
    u64*    sel  = (u64*)(ws + OFF_SEL);
    float4* boxes = (float4*)(ws + OFF_BOX);
    int*    cls  = (int*)(ws + OFF_CLS);
    u64*    rinit = (u64*)(ws + OFF_RINIT);
    int*    keep = (int*)(ws + OFF_KEEP);

    hipMemsetAsync(ws + OFF_HIST, 0, ZERO_BYTES, stream);

    k_score<<<(NIMG * CHUNKS_PER_IMG) / 2, 128, 0, stream>>>(clean, patch, keys);
    k_hist<<<dim3(NIMG, 16), 256, 0, stream>>>(keys, hist);
    k_thresh<<<NIMG, 1024, 0, stream>>>(hist, tbin);
    k_compact<<<dim3(NIMG, 16), 256, 0, stream>>>(keys, tbin, ccnt, cand);
    k_sort<<<NIMG, 1024, 0, stream>>>(cand, ccnt, sel);
    k_gather<<<NIMG, 1024, 0, stream>>>(clean, patch, sel, boxes, cls, rinit);
    k_nms_mask<<<dim3(NIMG, 16), 1024, 0, stream>>>(boxes, cls, mask);
    k_nms_scan<<<NIMG, 64, 0, stream>>>(mask, rinit, keep);
    k_match<<<8, 256, 0, stream>>>(boxes, cls, keep, sums, cnts);
    k_final<<<1, 64, 0, stream>>>(sums, cnts, out);
}

// Round 3
// 281.032 us; speedup vs baseline: 2.0438x; 1.5185x over previous
//
#include <hip/hip_runtime.h>

#define N_ANCH 25200
#define NCLS   80
#define ROW    85
#define NIMG   16
#define KMAX   1024
#define NBINS  4096
#define CAND_CAP 4096
#define CHUNKS_PER_IMG 394   // ceil(25200/64)
#define PCHUNK 64            // patch boxes per match block

typedef unsigned long long u64;
typedef unsigned int u32;

// ---------------- ws layout (bytes) ----------------
#define OFF_KEYS 0ull                      // 16*25200*8 = 3,225,600 ; reused as NMS mask (2 MB) after k_sort
#define OFF_HIST 3225600ull                // 16*4096*4  =   262,144
#define OFF_TBIN 3487744ull                // 16*4 = 64
#define OFF_CCNT 3487808ull                // 16*4 = 64
#define OFF_SUMS 3487872ull                // 8*4 = 32
#define OFF_CNTS 3487904ull                // 8*4 = 32
#define OFF_CAND 3487936ull                // 16*4096*8 = 524,288 ; reused as pmax (128 KB) after k_sort
#define OFF_SEL  4012224ull                // 16*1024*8 = 131,072
#define OFF_BOX  4143296ull                // 16*1024*16 = 262,144
#define OFF_CLS  4405440ull                // 16*1024*4 = 65,536
#define OFF_RINIT 4470976ull               // 16*16*8 = 2,048 (initial removal bitmask)
#define OFF_KEEP 4536512ull                // 16*1024*4 = 65,536
#define WS_NEED  4602048ull
#define ZERO_BYTES (262144ull + 64 + 64 + 32 + 32)   // hist..cnts contiguous

__device__ __forceinline__ int key_bin(u64 key) {
    u32 hi = (u32)(key >> 32);
    if (hi == 0u) return 0;
    float conf = __uint_as_float(hi - 0x40000000u);
    int b = 1 + (int)(conf * 4093.0f);
    return b > 4094 ? 4094 : b;
}

__device__ __forceinline__ u64 shfl64(u64 v, int src) {
    int lo = __shfl((int)(u32)(v & 0xffffffffull), src, 64);
    int hi = __shfl((int)(u32)(v >> 32), src, 64);
    return ((u64)(u32)hi << 32) | (u64)(u32)lo;
}

// K1: per-entry conf/cls/validity -> 64-bit sort key. Wave-staged coalesced loads.
__global__ __launch_bounds__(128) void k_score(const float* __restrict__ clean,
                                               const float* __restrict__ patch,
                                               u64* __restrict__ keys)
{
    __shared__ float lds[2][5440];   // 2 waves * 64 entries * 85 floats
    const int wv   = threadIdx.x >> 6;
    const int lane = threadIdx.x & 63;
    const int wave_id = blockIdx.x * 2 + wv;
    const int b     = wave_id / CHUNKS_PER_IMG;
    const int chunk = wave_id - b * CHUNKS_PER_IMG;
    const float* src = (b < 8) ? (clean + (size_t)b * N_ANCH * ROW)
                               : (patch + (size_t)(b - 8) * N_ANCH * ROW);
    const int base = chunk * 64;
    const int n_e  = min(64, N_ANCH - base);
    const int n4   = (n_e * ROW) >> 2;
    const float4* s4 = (const float4*)(src + (size_t)base * ROW);
    float4* l4 = (float4*)(&lds[wv][0]);
    for (int t = lane; t < n4; t += 64) l4[t] = s4[t];
    __syncthreads();
    if (lane < n_e) {
        const float* p = &lds[wv][lane * ROW];
        const float obj = p[4];
        float best = -1.0f; int bc = 0;
        #pragma unroll 8
        for (int d = 0; d < NCLS; ++d) {
            float s = p[5 + d] * obj;
            if (s > best) { best = s; bc = d; }
        }
        const float th = (b < 8) ? 0.25f : 0.001f;
        const bool valid = (obj > th) && (best > th);
        const u32 hi = valid ? (__float_as_uint(best) + 0x40000000u) : 0u;
        const u32 nbar = 32767u - (u32)(base + lane);
        keys[(size_t)b * N_ANCH + base + lane] =
            ((u64)hi << 32) | ((u64)nbar << 8) | (u64)(u32)bc;
    }
}

// K2: per-image histogram of conf bins
__global__ __launch_bounds__(256) void k_hist(const u64* __restrict__ keys,
                                              int* __restrict__ hist)
{
    __shared__ int h[NBINS];
    const int b = blockIdx.x;
    for (int i = threadIdx.x; i < NBINS; i += 256) h[i] = 0;
    __syncthreads();
    const int start = blockIdx.y * 1575;
    const u64* kp = keys + (size_t)b * N_ANCH;
    for (int i = start + threadIdx.x; i < start + 1575; i += 256)
        atomicAdd(&h[key_bin(kp[i])], 1);
    __syncthreads();
    for (int i = threadIdx.x; i < NBINS; i += 256)
        if (h[i]) atomicAdd(&hist[b * NBINS + i], h[i]);
}

// K3: per-image suffix-scan over bins -> threshold bin
__global__ __launch_bounds__(1024) void k_thresh(const int* __restrict__ hist,
                                                 int* __restrict__ tbin)
{
    __shared__ int arr[1024];
    const int b = blockIdx.x;
    const int t = threadIdx.x;
    int hh[4];
    hh[0] = hist[b * NBINS + 4 * t + 0];
    hh[1] = hist[b * NBINS + 4 * t + 1];
    hh[2] = hist[b * NBINS + 4 * t + 2];
    hh[3] = hist[b * NBINS + 4 * t + 3];
    const int r = hh[0] + hh[1] + hh[2] + hh[3];
    arr[t] = r;
    __syncthreads();
    for (int off = 1; off < 1024; off <<= 1) {
        int v = (t + off < 1024) ? arr[t + off] : 0;
        __syncthreads();
        arr[t] += v;
        __syncthreads();
    }
    const int K = (b < 8) ? 256 : 1024;
    int cb = arr[t] - r;
    for (int d = 3; d >= 0; --d) {
        int ca = cb + hh[d];
        if (cb < K && ca >= K) tbin[b] = 4 * t + d;
        cb = ca;
    }
}

// K4: compact candidates with bin >= T
__global__ __launch_bounds__(256) void k_compact(const u64* __restrict__ keys,
                                                 const int* __restrict__ tbin,
                                                 int* __restrict__ ccnt,
                                                 u64* __restrict__ cand)
{
    const int b = blockIdx.x;
    const int T = tbin[b];
    const u64* kp = keys + (size_t)b * N_ANCH;
    const int start = blockIdx.y * 1575;
    for (int i = start + threadIdx.x; i < start + 1575; i += 256) {
        u64 key = kp[i];
        if (key_bin(key) >= T) {
            int pos = atomicAdd(&ccnt[b], 1);
            if (pos < CAND_CAP) cand[(size_t)b * CAND_CAP + pos] = key;
        }
    }
}

// K5: per-image bitonic sort (descending) of candidates, emit top-K keys
__global__ __launch_bounds__(1024) void k_sort(const u64* __restrict__ cand,
                                               const int* __restrict__ ccnt,
                                               u64* __restrict__ sel)
{
    __shared__ u64 sk[CAND_CAP];   // 32 KB
    const int b = blockIdx.x;
    const int C = min(ccnt[b], CAND_CAP);
    const int t = threadIdx.x;
    #pragma unroll
    for (int p = 0; p < CAND_CAP / 1024; ++p) {
        int i = p * 1024 + t;
        sk[i] = (i < C) ? cand[(size_t)b * CAND_CAP + i] : 0ull;
    }
    __syncthreads();
    for (int k = 2; k <= CAND_CAP; k <<= 1) {
        for (int j = k >> 1; j > 0; j >>= 1) {
            #pragma unroll
            for (int p = 0; p < CAND_CAP / 1024; ++p) {
                int i = p * 1024 + t;
                int ixj = i ^ j;
                if (ixj > i) {
                    u64 a = sk[i], c = sk[ixj];
                    bool descSeg = ((i & k) == 0);
                    bool sw = descSeg ? (a < c) : (a > c);
                    if (sw) { sk[i] = c; sk[ixj] = a; }
                }
            }
            __syncthreads();
        }
    }
    const int K = (b < 8) ? 256 : 1024;
    if (t < K) sel[b * KMAX + t] = sk[t];
}

// K6: decode keys, gather boxes (xywh->xyxy), cls; ballot initial removal mask
__global__ __launch_bounds__(1024) void k_gather(const float* __restrict__ clean,
                                                 const float* __restrict__ patch,
                                                 const u64* __restrict__ sel,
                                                 float4* __restrict__ boxes,
                                                 int* __restrict__ cls,
                                                 u64* __restrict__ rinit)
{
    const int b = blockIdx.x;
    const int t = threadIdx.x;
    const int K = (b < 8) ? 256 : 1024;
    const u64 key = (t < K) ? sel[b * KMAX + t] : 0ull;
    const u32 hi = (u32)(key >> 32);
    const bool valid = (t < K) && (hi != 0u);
    u64 bal = __ballot(valid);
    if ((t & 63) == 0) rinit[b * 16 + (t >> 6)] = ~bal;
    if (t >= K) return;
    const int n = 32767 - (int)((key >> 8) & 0x7FFFu);
    const int c = (int)(key & 0x7Fu);
    const float* src = ((b < 8) ? (clean + (size_t)b * N_ANCH * ROW)
                                : (patch + (size_t)(b - 8) * N_ANCH * ROW)) + (size_t)n * ROW;
    const float x = src[0], y = src[1], w = src[2], h = src[3];
    boxes[b * KMAX + t] = make_float4(x - w * 0.5f, y - h * 0.5f, x + w * 0.5f, y + h * 0.5f);
    cls[b * KMAX + t] = c;
}

// K7a: parallel suppression-mask build. Wave = one 64-bit word column across 64 rows.
__global__ __launch_bounds__(1024) void k_nms_mask(const float4* __restrict__ boxes,
                                                   const int* __restrict__ cls,
                                                   u64* __restrict__ mask)
{
    __shared__ float4 bx[KMAX];
    __shared__ float ar[KMAX];
    const int b = blockIdx.x;
    const int K = (b < 8) ? 256 : 1024;
    const int row0 = blockIdx.y * 64;
    if (row0 >= K) return;                  // block-uniform
    const int t = threadIdx.x;
    for (int i = t; i < K; i += 1024) {
        float4 v = boxes[b * KMAX + i];
        float off = (float)cls[b * KMAX + i] * 4096.0f;
        v.x += off; v.y += off; v.z += off; v.w += off;
        bx[i] = v;
        ar[i] = (v.z - v.x) * (v.w - v.y);
    }
    __syncthreads();
    const int w   = t >> 6;                 // word column (wave-uniform)
    const int row = row0 + (t & 63);        // lane-distinct row
    u64* dst = mask + ((size_t)b * KMAX + row) * 16 + w;
    if (((w << 6) + 63) <= row0 && row0 > 0) { *dst = 0ull; return; }   // all j <= min row: zero word
    const float4 bi = bx[row];
    const float ai = ar[row];
    const int jbase = w << 6;
    u64 m = 0;
    #pragma unroll 8
    for (int k = 0; k < 64; ++k) {
        const int j = jbase + k;            // wave-uniform -> LDS broadcast
        const float4 bj = bx[j];
        const float ax = fmaxf(bi.x, bj.x), ay = fmaxf(bi.y, bj.y);
        const float bx2 = fminf(bi.z, bj.z), by2 = fminf(bi.w, bj.w);
        const float iw = fmaxf(bx2 - ax, 0.f), ih = fmaxf(by2 - ay, 0.f);
        const float inter = iw * ih;
        const float iou = inter / (ai + ar[j] - inter);
        if (j > row && iou > 0.45f) m |= (1ull << k);
    }
    *dst = m;
}

// K7b: serial scan, one wave per image, zero barriers. Lanes 0..15 own removal words.
__global__ __launch_bounds__(64) void k_nms_scan(const u64* __restrict__ mask,
                                                 const u64* __restrict__ rinit,
                                                 int* __restrict__ keep)
{
    const int b = blockIdx.x;
    const int K = (b < 8) ? 256 : 1024;
    const int W = K >> 6;
    const int lane = threadIdx.x;
    const int wl = lane & 15;               // lanes 16+ mirror words 0..15 (values unused)
    u64 w_remv = rinit[b * 16 + wl];
    const u64* mrow = mask + (size_t)b * KMAX * 16;
    #pragma unroll 2
    for (int i = 0; i < K; i += 4) {
        const u64* p = mrow + (size_t)i * 16 + wl;
        const u64 m0 = p[0], m1 = p[16], m2 = p[32], m3 = p[48];
        const int owner = i >> 6;
        const u64 ow  = shfl64(w_remv, owner);
        const u64 m0o = shfl64(m0, owner);
        const u64 m1o = shfl64(m1, owner);
        const u64 m2o = shfl64(m2, owner);
        const int b0 = i & 63;
        const bool k0 = !((ow >> b0) & 1);
        u64 acc = k0 ? m0o : 0ull;
        const bool k1 = !(((ow | acc) >> (b0 + 1)) & 1);
        if (k1) acc |= m1o;
        const bool k2 = !(((ow | acc) >> (b0 + 2)) & 1);
        if (k2) acc |= m2o;
        const bool k3 = !(((ow | acc) >> (b0 + 3)) & 1);
        w_remv |= (k0 ? m0 : 0ull) | (k1 ? m1 : 0ull) | (k2 ? m2 : 0ull) | (k3 ? m3 : 0ull);
    }
    if (lane < W) {
        for (int k = 0; k < 64; ++k)
            keep[b * KMAX + lane * 64 + k] = (int)(((w_remv >> k) & 1) ^ 1ull);
    }
}

// K8a: partial max IoU: block = (clean image, patch chunk of 64). Branchless inner loop.
__global__ __launch_bounds__(256) void k_match_partial(const float4* __restrict__ boxes,
                                                       const int* __restrict__ cls,
                                                       const int* __restrict__ keep,
                                                       float* __restrict__ pmax)
{
    __shared__ float4 pb[PCHUNK];
    __shared__ float par[PCHUNK];
    __shared__ int pcls[PCHUNK];
    const int c = blockIdx.x;        // clean image 0..7
    const int p = blockIdx.y;        // patch chunk 0..15
    const int bp = 8 + c;
    const int t = threadIdx.x;
    if (t < PCHUNK) {
        const int i = p * PCHUNK + t;
        const float4 v = boxes[bp * KMAX + i];
        pb[t] = v;
        par[t] = (v.z - v.x) * (v.w - v.y);
        pcls[t] = keep[bp * KMAX + i] ? cls[bp * KMAX + i] : -1;   // fold keep into class
    }
    __syncthreads();
    const float4 bc = boxes[c * KMAX + t];
    const int cc = cls[c * KMAX + t];
    const float area_c = (bc.z - bc.x) * (bc.w - bc.y);
    float tm = 0.f;
    #pragma unroll 8
    for (int i = 0; i < PCHUNK; ++i) {
        const float4 bi = pb[i];
        const float ax = fmaxf(bi.x, bc.x), ay = fmaxf(bi.y, bc.y);
        const float bx2 = fminf(bi.z, bc.z), by2 = fminf(bi.w, bc.w);
        const float iw = fmaxf(bx2 - ax, 0.f), ih = fmaxf(by2 - ay, 0.f);
        const float inter = iw * ih;
        const float iou = inter / (par[i] + area_c - inter);
        tm = fmaxf(tm, (pcls[i] == cc) ? iou : 0.f);
    }
    pmax[(c * 16 + p) * 256 + t] = tm;
}

// K8b: reduce over chunks, mask by clean keep, sum
__global__ __launch_bounds__(256) void k_match_reduce(const float* __restrict__ pmax,
                                                      const int* __restrict__ keep,
                                                      float* __restrict__ sums,
                                                      float* __restrict__ cnts)
{
    __shared__ float red[8];
    const int c = blockIdx.x;
    const int t = threadIdx.x;
    float tm = 0.f;
    #pragma unroll
    for (int p = 0; p < 16; ++p)
        tm = fmaxf(tm, pmax[(c * 16 + p) * 256 + t]);
    const int kc = keep[c * KMAX + t];
    float val = kc ? tm : 0.f;
    float cv  = kc ? 1.f : 0.f;
    for (int off = 32; off > 0; off >>= 1) {
        val += __shfl_down(val, off);
        cv  += __shfl_down(cv, off);
    }
    const int wv = t >> 6, lane = t & 63;
    if (lane == 0) { red[wv] = val; red[4 + wv] = cv; }
    __syncthreads();
    if (t == 0) {
        sums[c] = red[0] + red[1] + red[2] + red[3];
        cnts[c] = red[4] + red[5] + red[6] + red[7];
    }
}

// K9: scalar epilogue
__global__ void k_final(const float* __restrict__ sums,
                        const float* __restrict__ cnts,
                        float* __restrict__ out)
{
    if (threadIdx.x == 0 && blockIdx.x == 0) {
        float total = 0.f, cnt = 0.f;
        for (int c = 0; c < 8; ++c) { total += sums[c]; cnt += cnts[c]; }
        out[0] = (cnt > 0.f) ? (1.0f - total / fmaxf(cnt, 1.0f)) : 1.0f;
    }
}

extern "C" void kernel_launch(void* const* d_in, const int* in_sizes, int n_in,
                              void* d_out, int out_size, void* d_ws, size_t ws_size,
                              hipStream_t stream)
{
    if (ws_size < WS_NEED) return;
    const float* clean = (const float*)d_in[0];
    const float* patch = (const float*)d_in[1];
    float* out = (float*)d_out;
    char* ws = (char*)d_ws;

    u64*    keys = (u64*)(ws + OFF_KEYS);
    u64*    mask = (u64*)(ws + OFF_KEYS);   // reuses keys region after k_sort
    int*    hist = (int*)(ws + OFF_HIST);
    int*    tbin = (int*)(ws + OFF_TBIN);
    int*    ccnt = (int*)(ws + OFF_CCNT);
    float*  sums = (float*)(ws + OFF_SUMS);
    float*  cnts = (float*)(ws + OFF_CNTS);
    u64*    cand = (u64*)(ws + OFF_CAND);
    float*  pmax = (float*)(ws + OFF_CAND); // reuses cand region after k_sort
    u64*    sel  = (u64*)(ws + OFF_SEL);
    float4* boxes = (float4*)(ws + OFF_BOX);
    int*    cls  = (int*)(ws + OFF_CLS);
    u64*    rinit = (u64*)(ws + OFF_RINIT);
    int*    keep = (int*)(ws + OFF_KEEP);

    hipMemsetAsync(ws + OFF_HIST, 0, ZERO_BYTES, stream);

    k_score<<<(NIMG * CHUNKS_PER_IMG) / 2, 128, 0, stream>>>(clean, patch, keys);
    k_hist<<<dim3(NIMG, 16), 256, 0, stream>>>(keys, hist);
    k_thresh<<<NIMG, 1024, 0, stream>>>(hist, tbin);
    k_compact<<<dim3(NIMG, 16), 256, 0, stream>>>(keys, tbin, ccnt, cand);
    k_sort<<<NIMG, 1024, 0, stream>>>(cand, ccnt, sel);
    k_gather<<<NIMG, 1024, 0, stream>>>(clean, patch, sel, boxes, cls, rinit);
    k_nms_mask<<<dim3(NIMG, 16), 1024, 0, stream>>>(boxes, cls, mask);
    k_nms_scan<<<NIMG, 64, 0, stream>>>(mask, rinit, keep);
    k_match_partial<<<dim3(8, 16), 256, 0, stream>>>(boxes, cls, keep, pmax);
    k_match_reduce<<<8, 256, 0, stream>>>(pmax, keep, sums, cnts);
    k_final<<<1, 64, 0, stream>>>(sums, cnts, out);
}

// Round 4
// 240.835 us; speedup vs baseline: 2.3849x; 1.1669x over previous
//
#include <hip/hip_runtime.h>

#define N_ANCH 25200
#define NCLS   80
#define ROW    85
#define NIMG   16
#define KMAX   1024
#define NBINS  4096
#define CAND_CAP 4096
#define CHUNKS_PER_IMG 394   // ceil(25200/64)
#define PCHUNK 64            // patch boxes per match block

typedef unsigned long long u64;
typedef unsigned int u32;

// ---------------- ws layout (bytes) ----------------
#define OFF_KEYS 0ull                      // 16*25200*8 = 3,225,600 ; reused as NMS mask (2 MB) after k_sort
#define OFF_HIST 3225600ull                // 16*4096*4  =   262,144
#define OFF_TBIN 3487744ull                // 16*4 = 64
#define OFF_CCNT 3487808ull                // 16*4 = 64
#define OFF_SUMS 3487872ull                // 8*4 = 32
#define OFF_CNTS 3487904ull                // 8*4 = 32
#define OFF_CAND 3487936ull                // 16*4096*8 = 524,288 ; reused as pmax (128 KB) after k_sort
#define OFF_SEL  4012224ull                // 16*1024*8 = 131,072
#define OFF_BOX  4143296ull                // 16*1024*16 = 262,144
#define OFF_CLS  4405440ull                // 16*1024*4 = 65,536
#define OFF_RINIT 4470976ull               // 16*16*8 = 2,048 (initial removal bitmask)
#define OFF_KEEP 4536512ull                // 16*1024*4 = 65,536
#define WS_NEED  4602048ull
#define ZERO_BYTES (262144ull + 64 + 64 + 32 + 32)   // hist..cnts contiguous

__device__ __forceinline__ int key_bin(u64 key) {
    u32 hi = (u32)(key >> 32);
    if (hi == 0u) return 0;
    float conf = __uint_as_float(hi - 0x40000000u);
    int b = 1 + (int)(conf * 4093.0f);
    return b > 4094 ? 4094 : b;
}

__device__ __forceinline__ u64 shfl64(u64 v, int src) {
    int lo = __shfl((int)(u32)(v & 0xffffffffull), src, 64);
    int hi = __shfl((int)(u32)(v >> 32), src, 64);
    return ((u64)(u32)hi << 32) | (u64)(u32)lo;
}

// K1: per-entry conf/cls/validity -> 64-bit sort key. Wave-staged coalesced loads.
__global__ __launch_bounds__(128) void k_score(const float* __restrict__ clean,
                                               const float* __restrict__ patch,
                                               u64* __restrict__ keys)
{
    __shared__ float lds[2][5440];   // 2 waves * 64 entries * 85 floats
    const int wv   = threadIdx.x >> 6;
    const int lane = threadIdx.x & 63;
    const int wave_id = blockIdx.x * 2 + wv;
    const int b     = wave_id / CHUNKS_PER_IMG;
    const int chunk = wave_id - b * CHUNKS_PER_IMG;
    const float* src = (b < 8) ? (clean + (size_t)b * N_ANCH * ROW)
                               : (patch + (size_t)(b - 8) * N_ANCH * ROW);
    const int base = chunk * 64;
    const int n_e  = min(64, N_ANCH - base);
    const int n4   = (n_e * ROW) >> 2;
    const float4* s4 = (const float4*)(src + (size_t)base * ROW);
    float4* l4 = (float4*)(&lds[wv][0]);
    for (int t = lane; t < n4; t += 64) l4[t] = s4[t];
    __syncthreads();
    if (lane < n_e) {
        const float* p = &lds[wv][lane * ROW];
        const float obj = p[4];
        float best = -1.0f; int bc = 0;
        #pragma unroll 8
        for (int d = 0; d < NCLS; ++d) {
            float s = p[5 + d] * obj;
            if (s > best) { best = s; bc = d; }
        }
        const float th = (b < 8) ? 0.25f : 0.001f;
        const bool valid = (obj > th) && (best > th);
        const u32 hi = valid ? (__float_as_uint(best) + 0x40000000u) : 0u;
        const u32 nbar = 32767u - (u32)(base + lane);
        keys[(size_t)b * N_ANCH + base + lane] =
            ((u64)hi << 32) | ((u64)nbar << 8) | (u64)(u32)bc;
    }
}

// K2: per-image histogram of conf bins
__global__ __launch_bounds__(256) void k_hist(const u64* __restrict__ keys,
                                              int* __restrict__ hist)
{
    __shared__ int h[NBINS];
    const int b = blockIdx.x;
    for (int i = threadIdx.x; i < NBINS; i += 256) h[i] = 0;
    __syncthreads();
    const int start = blockIdx.y * 1575;
    const u64* kp = keys + (size_t)b * N_ANCH;
    for (int i = start + threadIdx.x; i < start + 1575; i += 256)
        atomicAdd(&h[key_bin(kp[i])], 1);
    __syncthreads();
    for (int i = threadIdx.x; i < NBINS; i += 256)
        if (h[i]) atomicAdd(&hist[b * NBINS + i], h[i]);
}

// K3: per-image suffix-scan over bins -> threshold bin
__global__ __launch_bounds__(1024) void k_thresh(const int* __restrict__ hist,
                                                 int* __restrict__ tbin)
{
    __shared__ int arr[1024];
    const int b = blockIdx.x;
    const int t = threadIdx.x;
    int hh[4];
    hh[0] = hist[b * NBINS + 4 * t + 0];
    hh[1] = hist[b * NBINS + 4 * t + 1];
    hh[2] = hist[b * NBINS + 4 * t + 2];
    hh[3] = hist[b * NBINS + 4 * t + 3];
    const int r = hh[0] + hh[1] + hh[2] + hh[3];
    arr[t] = r;
    __syncthreads();
    for (int off = 1; off < 1024; off <<= 1) {
        int v = (t + off < 1024) ? arr[t + off] : 0;
        __syncthreads();
        arr[t] += v;
        __syncthreads();
    }
    const int K = (b < 8) ? 256 : 1024;
    int cb = arr[t] - r;
    for (int d = 3; d >= 0; --d) {
        int ca = cb + hh[d];
        if (cb < K && ca >= K) tbin[b] = 4 * t + d;
        cb = ca;
    }
}

// K4: compact candidates with bin >= T
__global__ __launch_bounds__(256) void k_compact(const u64* __restrict__ keys,
                                                 const int* __restrict__ tbin,
                                                 int* __restrict__ ccnt,
                                                 u64* __restrict__ cand)
{
    const int b = blockIdx.x;
    const int T = tbin[b];
    const u64* kp = keys + (size_t)b * N_ANCH;
    const int start = blockIdx.y * 1575;
    for (int i = start + threadIdx.x; i < start + 1575; i += 256) {
        u64 key = kp[i];
        if (key_bin(key) >= T) {
            int pos = atomicAdd(&ccnt[b], 1);
            if (pos < CAND_CAP) cand[(size_t)b * CAND_CAP + pos] = key;
        }
    }
}

// K5: per-image bitonic sort (descending) of candidates, emit top-K keys
__global__ __launch_bounds__(1024) void k_sort(const u64* __restrict__ cand,
                                               const int* __restrict__ ccnt,
                                               u64* __restrict__ sel)
{
    __shared__ u64 sk[CAND_CAP];   // 32 KB
    const int b = blockIdx.x;
    const int C = min(ccnt[b], CAND_CAP);
    const int t = threadIdx.x;
    #pragma unroll
    for (int p = 0; p < CAND_CAP / 1024; ++p) {
        int i = p * 1024 + t;
        sk[i] = (i < C) ? cand[(size_t)b * CAND_CAP + i] : 0ull;
    }
    __syncthreads();
    for (int k = 2; k <= CAND_CAP; k <<= 1) {
        for (int j = k >> 1; j > 0; j >>= 1) {
            #pragma unroll
            for (int p = 0; p < CAND_CAP / 1024; ++p) {
                int i = p * 1024 + t;
                int ixj = i ^ j;
                if (ixj > i) {
                    u64 a = sk[i], c = sk[ixj];
                    bool descSeg = ((i & k) == 0);
                    bool sw = descSeg ? (a < c) : (a > c);
                    if (sw) { sk[i] = c; sk[ixj] = a; }
                }
            }
            __syncthreads();
        }
    }
    const int K = (b < 8) ? 256 : 1024;
    if (t < K) sel[b * KMAX + t] = sk[t];
}

// K6: decode keys, gather boxes (xywh->xyxy), cls; ballot initial removal mask
__global__ __launch_bounds__(1024) void k_gather(const float* __restrict__ clean,
                                                 const float* __restrict__ patch,
                                                 const u64* __restrict__ sel,
                                                 float4* __restrict__ boxes,
                                                 int* __restrict__ cls,
                                                 u64* __restrict__ rinit)
{
    const int b = blockIdx.x;
    const int t = threadIdx.x;
    const int K = (b < 8) ? 256 : 1024;
    const u64 key = (t < K) ? sel[b * KMAX + t] : 0ull;
    const u32 hi = (u32)(key >> 32);
    const bool valid = (t < K) && (hi != 0u);
    u64 bal = __ballot(valid);
    if ((t & 63) == 0) rinit[b * 16 + (t >> 6)] = ~bal;
    if (t >= K) return;
    const int n = 32767 - (int)((key >> 8) & 0x7FFFu);
    const int c = (int)(key & 0x7Fu);
    const float* src = ((b < 8) ? (clean + (size_t)b * N_ANCH * ROW)
                                : (patch + (size_t)(b - 8) * N_ANCH * ROW)) + (size_t)n * ROW;
    const float x = src[0], y = src[1], w = src[2], h = src[3];
    boxes[b * KMAX + t] = make_float4(x - w * 0.5f, y - h * 0.5f, x + w * 0.5f, y + h * 0.5f);
    cls[b * KMAX + t] = c;
}

// K7a: parallel suppression-mask build. Wave = one 64-bit word column across 64 rows.
__global__ __launch_bounds__(1024) void k_nms_mask(const float4* __restrict__ boxes,
                                                   const int* __restrict__ cls,
                                                   u64* __restrict__ mask)
{
    __shared__ float4 bx[KMAX];
    __shared__ float ar[KMAX];
    const int b = blockIdx.x;
    const int K = (b < 8) ? 256 : 1024;
    const int row0 = blockIdx.y * 64;
    if (row0 >= K) return;                  // block-uniform
    const int t = threadIdx.x;
    for (int i = t; i < K; i += 1024) {
        float4 v = boxes[b * KMAX + i];
        float off = (float)cls[b * KMAX + i] * 4096.0f;
        v.x += off; v.y += off; v.z += off; v.w += off;
        bx[i] = v;
        ar[i] = (v.z - v.x) * (v.w - v.y);
    }
    __syncthreads();
    const int w   = t >> 6;                 // word column (wave-uniform)
    const int row = row0 + (t & 63);        // lane-distinct row
    u64* dst = mask + ((size_t)b * KMAX + row) * 16 + w;
    if (((w << 6) + 63) <= row0 && row0 > 0) { *dst = 0ull; return; }   // all j <= min row: zero word
    const float4 bi = bx[row];
    const float ai = ar[row];
    const int jbase = w << 6;
    u64 m = 0;
    #pragma unroll 8
    for (int k = 0; k < 64; ++k) {
        const int j = jbase + k;            // wave-uniform -> LDS broadcast
        const float4 bj = bx[j];
        const float ax = fmaxf(bi.x, bj.x), ay = fmaxf(bi.y, bj.y);
        const float bx2 = fminf(bi.z, bj.z), by2 = fminf(bi.w, bj.w);
        const float iw = fmaxf(bx2 - ax, 0.f), ih = fmaxf(by2 - ay, 0.f);
        const float inter = iw * ih;
        const float iou = inter / (ai + ar[j] - inter);
        if (j > row && iou > 0.45f) m |= (1ull << k);
    }
    *dst = m;
}

// K7b: serial scan, one block per image. Whole mask staged to LDS first (bulk
// coalesced read), then wave 0 scans from LDS — removes the per-iteration
// HBM round-trip (was ~840 cyc/iter). Zero barriers inside the scan.
__global__ __launch_bounds__(1024) void k_nms_scan(const u64* __restrict__ mask,
                                                   const u64* __restrict__ rinit,
                                                   int* __restrict__ keep)
{
    extern __shared__ u64 smask[];          // 128 KB (patch) / 16 KB (clean)
    const int b = blockIdx.x;
    const int K = (b < 8) ? 256 : 1024;
    const int W = K >> 6;
    const int t = threadIdx.x;
    // stage mask[b] into LDS
    {
        const float4* s4 = (const float4*)(mask + (size_t)b * KMAX * 16);
        float4* d4 = (float4*)smask;
        const int n4 = (K * 16) >> 1;       // 2 u64 per float4
        for (int i = t; i < n4; i += 1024) d4[i] = s4[i];
    }
    __syncthreads();
    if (t >= 64) return;
    const int lane = t;
    const int wl = lane & 15;               // lanes 16+ mirror words 0..15 (values unused)
    u64 w_remv = rinit[b * 16 + wl];
    #pragma unroll 4
    for (int i = 0; i < K; i += 4) {
        const u64* p = smask + (size_t)i * 16 + wl;
        const u64 m0 = p[0], m1 = p[16], m2 = p[32], m3 = p[48];
        const int owner = i >> 6;
        const u64 ow  = shfl64(w_remv, owner);
        const u64 m0o = shfl64(m0, owner);
        const u64 m1o = shfl64(m1, owner);
        const u64 m2o = shfl64(m2, owner);
        const int b0 = i & 63;
        const bool k0 = !((ow >> b0) & 1);
        u64 acc = k0 ? m0o : 0ull;
        const bool k1 = !(((ow | acc) >> (b0 + 1)) & 1);
        if (k1) acc |= m1o;
        const bool k2 = !(((ow | acc) >> (b0 + 2)) & 1);
        if (k2) acc |= m2o;
        const bool k3 = !(((ow | acc) >> (b0 + 3)) & 1);
        w_remv |= (k0 ? m0 : 0ull) | (k1 ? m1 : 0ull) | (k2 ? m2 : 0ull) | (k3 ? m3 : 0ull);
    }
    if (lane < W) {
        for (int k = 0; k < 64; ++k)
            keep[b * KMAX + lane * 64 + k] = (int)(((w_remv >> k) & 1) ^ 1ull);
    }
}

// K8a: partial max IoU: block = (clean image, patch chunk of 64). Branchless inner loop.
__global__ __launch_bounds__(256) void k_match_partial(const float4* __restrict__ boxes,
                                                       const int* __restrict__ cls,
                                                       const int* __restrict__ keep,
                                                       float* __restrict__ pmax)
{
    __shared__ float4 pb[PCHUNK];
    __shared__ float par[PCHUNK];
    __shared__ int pcls[PCHUNK];
    const int c = blockIdx.x;        // clean image 0..7
    const int p = blockIdx.y;        // patch chunk 0..15
    const int bp = 8 + c;
    const int t = threadIdx.x;
    if (t < PCHUNK) {
        const int i = p * PCHUNK + t;
        const float4 v = boxes[bp * KMAX + i];
        pb[t] = v;
        par[t] = (v.z - v.x) * (v.w - v.y);
        pcls[t] = keep[bp * KMAX + i] ? cls[bp * KMAX + i] : -1;   // fold keep into class
    }
    __syncthreads();
    const float4 bc = boxes[c * KMAX + t];
    const int cc = cls[c * KMAX + t];
    const float area_c = (bc.z - bc.x) * (bc.w - bc.y);
    float tm = 0.f;
    #pragma unroll 8
    for (int i = 0; i < PCHUNK; ++i) {
        const float4 bi = pb[i];
        const float ax = fmaxf(bi.x, bc.x), ay = fmaxf(bi.y, bc.y);
        const float bx2 = fminf(bi.z, bc.z), by2 = fminf(bi.w, bc.w);
        const float iw = fmaxf(bx2 - ax, 0.f), ih = fmaxf(by2 - ay, 0.f);
        const float inter = iw * ih;
        const float iou = inter / (par[i] + area_c - inter);
        tm = fmaxf(tm, (pcls[i] == cc) ? iou : 0.f);
    }
    pmax[(c * 16 + p) * 256 + t] = tm;
}

// K8b: reduce over chunks, mask by clean keep, sum
__global__ __launch_bounds__(256) void k_match_reduce(const float* __restrict__ pmax,
                                                      const int* __restrict__ keep,
                                                      float* __restrict__ sums,
                                                      float* __restrict__ cnts)
{
    __shared__ float red[8];
    const int c = blockIdx.x;
    const int t = threadIdx.x;
    float tm = 0.f;
    #pragma unroll
    for (int p = 0; p < 16; ++p)
        tm = fmaxf(tm, pmax[(c * 16 + p) * 256 + t]);
    const int kc = keep[c * KMAX + t];
    float val = kc ? tm : 0.f;
    float cv  = kc ? 1.f : 0.f;
    for (int off = 32; off > 0; off >>= 1) {
        val += __shfl_down(val, off);
        cv  += __shfl_down(cv, off);
    }
    const int wv = t >> 6, lane = t & 63;
    if (lane == 0) { red[wv] = val; red[4 + wv] = cv; }
    __syncthreads();
    if (t == 0) {
        sums[c] = red[0] + red[1] + red[2] + red[3];
        cnts[c] = red[4] + red[5] + red[6] + red[7];
    }
}

// K9: scalar epilogue
__global__ void k_final(const float* __restrict__ sums,
                        const float* __restrict__ cnts,
                        float* __restrict__ out)
{
    if (threadIdx.x == 0 && blockIdx.x == 0) {
        float total = 0.f, cnt = 0.f;
        for (int c = 0; c < 8; ++c) { total += sums[c]; cnt += cnts[c]; }
        out[0] = (cnt > 0.f) ? (1.0f - total / fmaxf(cnt, 1.0f)) : 1.0f;
    }
}

extern "C" void kernel_launch(void* const* d_in, const int* in_sizes, int n_in,
                              void* d_out, int out_size, void* d_ws, size_t ws_size,
                              hipStream_t stream)
{
    if (ws_size < WS_NEED) return;
    const float* clean = (const float*)d_in[0];
    const float* patch = (const float*)d_in[1];
    float* out = (float*)d_out;
    char* ws = (char*)d_ws;

    u64*    keys = (u64*)(ws + OFF_KEYS);
    u64*    mask = (u64*)(ws + OFF_KEYS);   // reuses keys region after k_sort
    int*    hist = (int*)(ws + OFF_HIST);
    int*    tbin = (int*)(ws + OFF_TBIN);
    int*    ccnt = (int*)(ws + OFF_CCNT);
    float*  sums = (float*)(ws + OFF_SUMS);
    float*  cnts = (float*)(ws + OFF_CNTS);
    u64*    cand = (u64*)(ws + OFF_CAND);
    float*  pmax = (float*)(ws + OFF_CAND); // reuses cand region after k_sort
    u64*    sel  = (u64*)(ws + OFF_SEL);
    float4* boxes = (float4*)(ws + OFF_BOX);
    int*    cls  = (int*)(ws + OFF_CLS);
    u64*    rinit = (u64*)(ws + OFF_RINIT);
    int*    keep = (int*)(ws + OFF_KEEP);

    hipMemsetAsync(ws + OFF_HIST, 0, ZERO_BYTES, stream);

    k_score<<<(NIMG * CHUNKS_PER_IMG) / 2, 128, 0, stream>>>(clean, patch, keys);
    k_hist<<<dim3(NIMG, 16), 256, 0, stream>>>(keys, hist);
    k_thresh<<<NIMG, 1024, 0, stream>>>(hist, tbin);
    k_compact<<<dim3(NIMG, 16), 256, 0, stream>>>(keys, tbin, ccnt, cand);
    k_sort<<<NIMG, 1024, 0, stream>>>(cand, ccnt, sel);
    k_gather<<<NIMG, 1024, 0, stream>>>(clean, patch, sel, boxes, cls, rinit);
    k_nms_mask<<<dim3(NIMG, 16), 1024, 0, stream>>>(boxes, cls, mask);
    k_nms_scan<<<NIMG, 1024, 131072, stream>>>(mask, rinit, keep);
    k_match_partial<<<dim3(8, 16), 256, 0, stream>>>(boxes, cls, keep, pmax);
    k_match_reduce<<<8, 256, 0, stream>>>(pmax, keep, sums, cnts);
    k_final<<<1, 64, 0, stream>>>(sums, cnts, out);
}

// Round 5
// 219.451 us; speedup vs baseline: 2.6173x; 1.0974x over previous
//
#include <hip/hip_runtime.h>

#define N_ANCH 25200
#define NCLS   80
#define ROW    85
#define NIMG   16
#define KMAX   1024
#define NBINS  4096
#define CAND_CAP 4096
#define SROWS   48           // rows per wave in k_score (25200 = 525*48)
#define SCHUNKS 525
#define SFLOATS (SROWS*ROW)  // 4080 floats = 16320 B per wave
#define PCHUNK 64            // patch boxes per match block

typedef unsigned long long u64;
typedef unsigned int u32;

// ---------------- ws layout (bytes) ----------------
#define OFF_KEYS 0ull                      // 16*25200*8 = 3,225,600 ; reused as NMS mask (2 MB) after k_sort
#define OFF_HIST 3225600ull                // 16*4096*4  =   262,144
#define OFF_TBIN 3487744ull                // 16*4 = 64
#define OFF_CCNT 3487808ull                // 16*4 = 64
#define OFF_SUMS 3487872ull                // 8*4 = 32
#define OFF_CNTS 3487904ull                // 8*4 = 32
#define OFF_CAND 3487936ull                // 16*4096*8 = 524,288 ; reused as pmax (128 KB) after k_sort
#define OFF_SEL  4012224ull                // 16*1024*8 = 131,072
#define OFF_BOX  4143296ull                // 16*1024*16 = 262,144
#define OFF_CLS  4405440ull                // 16*1024*4 = 65,536
#define OFF_RINIT 4470976ull               // 16*16*8 = 2,048 (initial removal bitmask)
#define OFF_KEEP 4536512ull                // 16*1024*4 = 65,536
#define WS_NEED  4602048ull
#define ZERO_BYTES (262144ull + 64 + 64 + 32 + 32)   // hist..cnts contiguous

__device__ __forceinline__ int key_bin(u64 key) {
    u32 hi = (u32)(key >> 32);
    if (hi == 0u) return 0;
    float conf = __uint_as_float(hi - 0x40000000u);
    int b = 1 + (int)(conf * 4093.0f);
    return b > 4094 ? 4094 : b;
}

__device__ __forceinline__ u64 shfl64(u64 v, int src) {
    int lo = __shfl((int)(u32)(v & 0xffffffffull), src, 64);
    int hi = __shfl((int)(u32)(v >> 32), src, 64);
    return ((u64)(u32)hi << 32) | (u64)(u32)lo;
}

// K1: per-entry conf/cls/validity -> 64-bit sort key.
// Staging via global_load_lds DMA (fire-and-forget, ~16 KB in flight per wave),
// wave-local vmcnt wait (no barriers). 48 rows/wave, 25200 = 525*48 exactly.
__global__ __launch_bounds__(128) void k_score(const float* __restrict__ clean,
                                               const float* __restrict__ patch,
                                               u64* __restrict__ keys)
{
    __shared__ float lds[2][SFLOATS];    // 32,640 B -> 5 blocks/CU (10 waves/CU)
    const int wv   = threadIdx.x >> 6;
    const int lane = threadIdx.x & 63;
    const int wave_id = blockIdx.x * 2 + wv;
    const int b     = wave_id / SCHUNKS;
    const int chunk = wave_id - b * SCHUNKS;
    const float* src = (b < 8) ? (clean + (size_t)b * N_ANCH * ROW)
                               : (patch + (size_t)(b - 8) * N_ANCH * ROW);
    const int base = chunk * SROWS;
    const float* g = src + (size_t)base * ROW;
    float* lbuf = &lds[wv][0];
    // 15 x 1KB DMA: lane i lands at ldsbase + i*16 (linear layout == source order)
    #pragma unroll
    for (int t = 0; t < 15; ++t)
        __builtin_amdgcn_global_load_lds(
            (const __attribute__((address_space(1))) void*)(g + t * 256 + lane * 4),
            (__attribute__((address_space(3))) void*)(lbuf + t * 256), 16, 0, 0);
    // tail 960 B (floats 3840..4080): 60 lanes x float4 via registers
    if (lane < 60) {
        const float4 v = *(const float4*)(g + 3840 + lane * 4);
        *(float4*)(lbuf + 3840 + lane * 4) = v;
    }
    asm volatile("s_waitcnt vmcnt(0) lgkmcnt(0)" ::: "memory");
    __builtin_amdgcn_sched_barrier(0);
    if (lane < SROWS) {
        const float* p = lbuf + lane * ROW;
        const float obj = p[4];
        float best = -1.0f; int bc = 0;
        #pragma unroll 8
        for (int d = 0; d < NCLS; ++d) {
            float s = p[5 + d] * obj;
            if (s > best) { best = s; bc = d; }
        }
        const float th = (b < 8) ? 0.25f : 0.001f;
        const bool valid = (obj > th) && (best > th);
        const u32 hi = valid ? (__float_as_uint(best) + 0x40000000u) : 0u;
        const u32 nbar = 32767u - (u32)(base + lane);
        keys[(size_t)b * N_ANCH + base + lane] =
            ((u64)hi << 32) | ((u64)nbar << 8) | (u64)(u32)bc;
    }
}

// K2: per-image histogram of conf bins
__global__ __launch_bounds__(256) void k_hist(const u64* __restrict__ keys,
                                              int* __restrict__ hist)
{
    __shared__ int h[NBINS];
    const int b = blockIdx.x;
    for (int i = threadIdx.x; i < NBINS; i += 256) h[i] = 0;
    __syncthreads();
    const int start = blockIdx.y * 1575;
    const u64* kp = keys + (size_t)b * N_ANCH;
    for (int i = start + threadIdx.x; i < start + 1575; i += 256)
        atomicAdd(&h[key_bin(kp[i])], 1);
    __syncthreads();
    for (int i = threadIdx.x; i < NBINS; i += 256)
        if (h[i]) atomicAdd(&hist[b * NBINS + i], h[i]);
}

// K3: per-image suffix-scan over bins -> threshold bin
__global__ __launch_bounds__(1024) void k_thresh(const int* __restrict__ hist,
                                                 int* __restrict__ tbin)
{
    __shared__ int arr[1024];
    const int b = blockIdx.x;
    const int t = threadIdx.x;
    int hh[4];
    hh[0] = hist[b * NBINS + 4 * t + 0];
    hh[1] = hist[b * NBINS + 4 * t + 1];
    hh[2] = hist[b * NBINS + 4 * t + 2];
    hh[3] = hist[b * NBINS + 4 * t + 3];
    const int r = hh[0] + hh[1] + hh[2] + hh[3];
    arr[t] = r;
    __syncthreads();
    for (int off = 1; off < 1024; off <<= 1) {
        int v = (t + off < 1024) ? arr[t + off] : 0;
        __syncthreads();
        arr[t] += v;
        __syncthreads();
    }
    const int K = (b < 8) ? 256 : 1024;
    int cb = arr[t] - r;
    for (int d = 3; d >= 0; --d) {
        int ca = cb + hh[d];
        if (cb < K && ca >= K) tbin[b] = 4 * t + d;
        cb = ca;
    }
}

// K4: compact candidates with bin >= T
__global__ __launch_bounds__(256) void k_compact(const u64* __restrict__ keys,
                                                 const int* __restrict__ tbin,
                                                 int* __restrict__ ccnt,
                                                 u64* __restrict__ cand)
{
    const int b = blockIdx.x;
    const int T = tbin[b];
    const u64* kp = keys + (size_t)b * N_ANCH;
    const int start = blockIdx.y * 1575;
    for (int i = start + threadIdx.x; i < start + 1575; i += 256) {
        u64 key = kp[i];
        if (key_bin(key) >= T) {
            int pos = atomicAdd(&ccnt[b], 1);
            if (pos < CAND_CAP) cand[(size_t)b * CAND_CAP + pos] = key;
        }
    }
}

// K5: per-image bitonic sort (descending) of candidates, emit top-K keys
__global__ __launch_bounds__(1024) void k_sort(const u64* __restrict__ cand,
                                               const int* __restrict__ ccnt,
                                               u64* __restrict__ sel)
{
    __shared__ u64 sk[CAND_CAP];   // 32 KB
    const int b = blockIdx.x;
    const int C = min(ccnt[b], CAND_CAP);
    const int t = threadIdx.x;
    #pragma unroll
    for (int p = 0; p < CAND_CAP / 1024; ++p) {
        int i = p * 1024 + t;
        sk[i] = (i < C) ? cand[(size_t)b * CAND_CAP + i] : 0ull;
    }
    __syncthreads();
    for (int k = 2; k <= CAND_CAP; k <<= 1) {
        for (int j = k >> 1; j > 0; j >>= 1) {
            #pragma unroll
            for (int p = 0; p < CAND_CAP / 1024; ++p) {
                int i = p * 1024 + t;
                int ixj = i ^ j;
                if (ixj > i) {
                    u64 a = sk[i], c = sk[ixj];
                    bool descSeg = ((i & k) == 0);
                    bool sw = descSeg ? (a < c) : (a > c);
                    if (sw) { sk[i] = c; sk[ixj] = a; }
                }
            }
            __syncthreads();
        }
    }
    const int K = (b < 8) ? 256 : 1024;
    if (t < K) sel[b * KMAX + t] = sk[t];
}

// K6: decode keys, gather boxes (xywh->xyxy), cls; ballot initial removal mask
__global__ __launch_bounds__(1024) void k_gather(const float* __restrict__ clean,
                                                 const float* __restrict__ patch,
                                                 const u64* __restrict__ sel,
                                                 float4* __restrict__ boxes,
                                                 int* __restrict__ cls,
                                                 u64* __restrict__ rinit)
{
    const int b = blockIdx.x;
    const int t = threadIdx.x;
    const int K = (b < 8) ? 256 : 1024;
    const u64 key = (t < K) ? sel[b * KMAX + t] : 0ull;
    const u32 hi = (u32)(key >> 32);
    const bool valid = (t < K) && (hi != 0u);
    u64 bal = __ballot(valid);
    if ((t & 63) == 0) rinit[b * 16 + (t >> 6)] = ~bal;
    if (t >= K) return;
    const int n = 32767 - (int)((key >> 8) & 0x7FFFu);
    const int c = (int)(key & 0x7Fu);
    const float* src = ((b < 8) ? (clean + (size_t)b * N_ANCH * ROW)
                                : (patch + (size_t)(b - 8) * N_ANCH * ROW)) + (size_t)n * ROW;
    const float x = src[0], y = src[1], w = src[2], h = src[3];
    boxes[b * KMAX + t] = make_float4(x - w * 0.5f, y - h * 0.5f, x + w * 0.5f, y + h * 0.5f);
    cls[b * KMAX + t] = c;
}

// K7a: parallel suppression-mask build. Wave = one 64-bit word column across 64 rows.
__global__ __launch_bounds__(1024) void k_nms_mask(const float4* __restrict__ boxes,
                                                   const int* __restrict__ cls,
                                                   u64* __restrict__ mask)
{
    __shared__ float4 bx[KMAX];
    __shared__ float ar[KMAX];
    const int b = blockIdx.x;
    const int K = (b < 8) ? 256 : 1024;
    const int row0 = blockIdx.y * 64;
    if (row0 >= K) return;                  // block-uniform
    const int t = threadIdx.x;
    for (int i = t; i < K; i += 1024) {
        float4 v = boxes[b * KMAX + i];
        float off = (float)cls[b * KMAX + i] * 4096.0f;
        v.x += off; v.y += off; v.z += off; v.w += off;
        bx[i] = v;
        ar[i] = (v.z - v.x) * (v.w - v.y);
    }
    __syncthreads();
    const int w   = t >> 6;                 // word column (wave-uniform)
    const int row = row0 + (t & 63);        // lane-distinct row
    u64* dst = mask + ((size_t)b * KMAX + row) * 16 + w;
    if (((w << 6) + 63) <= row0 && row0 > 0) { *dst = 0ull; return; }   // all j <= min row: zero word
    const float4 bi = bx[row];
    const float ai = ar[row];
    const int jbase = w << 6;
    u64 m = 0;
    #pragma unroll 8
    for (int k = 0; k < 64; ++k) {
        const int j = jbase + k;            // wave-uniform -> LDS broadcast
        const float4 bj = bx[j];
        const float ax = fmaxf(bi.x, bj.x), ay = fmaxf(bi.y, bj.y);
        const float bx2 = fminf(bi.z, bj.z), by2 = fminf(bi.w, bj.w);
        const float iw = fmaxf(bx2 - ax, 0.f), ih = fmaxf(by2 - ay, 0.f);
        const float inter = iw * ih;
        const float iou = inter / (ai + ar[j] - inter);
        if (j > row && iou > 0.45f) m |= (1ull << k);
    }
    *dst = m;
}

// K7b: serial scan, one block per image. Whole mask staged to LDS first (bulk
// coalesced read), then wave 0 scans from LDS. Zero barriers inside the scan.
__global__ __launch_bounds__(1024) void k_nms_scan(const u64* __restrict__ mask,
                                                   const u64* __restrict__ rinit,
                                                   int* __restrict__ keep)
{
    extern __shared__ u64 smask[];          // 128 KB (patch) / 16 KB (clean)
    const int b = blockIdx.x;
    const int K = (b < 8) ? 256 : 1024;
    const int W = K >> 6;
    const int t = threadIdx.x;
    {
        const float4* s4 = (const float4*)(mask + (size_t)b * KMAX * 16);
        float4* d4 = (float4*)smask;
        const int n4 = (K * 16) >> 1;       // 2 u64 per float4
        for (int i = t; i < n4; i += 1024) d4[i] = s4[i];
    }
    __syncthreads();
    if (t >= 64) return;
    const int lane = t;
    const int wl = lane & 15;               // lanes 16+ mirror words 0..15 (values unused)
    u64 w_remv = rinit[b * 16 + wl];
    #pragma unroll 4
    for (int i = 0; i < K; i += 4) {
        const u64* p = smask + (size_t)i * 16 + wl;
        const u64 m0 = p[0], m1 = p[16], m2 = p[32], m3 = p[48];
        const int owner = i >> 6;
        const u64 ow  = shfl64(w_remv, owner);
        const u64 m0o = shfl64(m0, owner);
        const u64 m1o = shfl64(m1, owner);
        const u64 m2o = shfl64(m2, owner);
        const int b0 = i & 63;
        const bool k0 = !((ow >> b0) & 1);
        u64 acc = k0 ? m0o : 0ull;
        const bool k1 = !(((ow | acc) >> (b0 + 1)) & 1);
        if (k1) acc |= m1o;
        const bool k2 = !(((ow | acc) >> (b0 + 2)) & 1);
        if (k2) acc |= m2o;
        const bool k3 = !(((ow | acc) >> (b0 + 3)) & 1);
        w_remv |= (k0 ? m0 : 0ull) | (k1 ? m1 : 0ull) | (k2 ? m2 : 0ull) | (k3 ? m3 : 0ull);
    }
    if (lane < W) {
        for (int k = 0; k < 64; ++k)
            keep[b * KMAX + lane * 64 + k] = (int)(((w_remv >> k) & 1) ^ 1ull);
    }
}

// K8a: partial max IoU: block = (clean image, patch chunk of 64). Branchless inner loop.
__global__ __launch_bounds__(256) void k_match_partial(const float4* __restrict__ boxes,
                                                       const int* __restrict__ cls,
                                                       const int* __restrict__ keep,
                                                       float* __restrict__ pmax)
{
    __shared__ float4 pb[PCHUNK];
    __shared__ float par[PCHUNK];
    __shared__ int pcls[PCHUNK];
    const int c = blockIdx.x;        // clean image 0..7
    const int p = blockIdx.y;        // patch chunk 0..15
    const int bp = 8 + c;
    const int t = threadIdx.x;
    if (t < PCHUNK) {
        const int i = p * PCHUNK + t;
        const float4 v = boxes[bp * KMAX + i];
        pb[t] = v;
        par[t] = (v.z - v.x) * (v.w - v.y);
        pcls[t] = keep[bp * KMAX + i] ? cls[bp * KMAX + i] : -1;   // fold keep into class
    }
    __syncthreads();
    const float4 bc = boxes[c * KMAX + t];
    const int cc = cls[c * KMAX + t];
    const float area_c = (bc.z - bc.x) * (bc.w - bc.y);
    float tm = 0.f;
    #pragma unroll 8
    for (int i = 0; i < PCHUNK; ++i) {
        const float4 bi = pb[i];
        const float ax = fmaxf(bi.x, bc.x), ay = fmaxf(bi.y, bc.y);
        const float bx2 = fminf(bi.z, bc.z), by2 = fminf(bi.w, bc.w);
        const float iw = fmaxf(bx2 - ax, 0.f), ih = fmaxf(by2 - ay, 0.f);
        const float inter = iw * ih;
        const float iou = inter / (par[i] + area_c - inter);
        tm = fmaxf(tm, (pcls[i] == cc) ? iou : 0.f);
    }
    pmax[(c * 16 + p) * 256 + t] = tm;
}

// K8b: reduce over chunks, mask by clean keep, sum
__global__ __launch_bounds__(256) void k_match_reduce(const float* __restrict__ pmax,
                                                      const int* __restrict__ keep,
                                                      float* __restrict__ sums,
                                                      float* __restrict__ cnts)
{
    __shared__ float red[8];
    const int c = blockIdx.x;
    const int t = threadIdx.x;
    float tm = 0.f;
    #pragma unroll
    for (int p = 0; p < 16; ++p)
        tm = fmaxf(tm, pmax[(c * 16 + p) * 256 + t]);
    const int kc = keep[c * KMAX + t];
    float val = kc ? tm : 0.f;
    float cv  = kc ? 1.f : 0.f;
    for (int off = 32; off > 0; off >>= 1) {
        val += __shfl_down(val, off);
        cv  += __shfl_down(cv, off);
    }
    const int wv = t >> 6, lane = t & 63;
    if (lane == 0) { red[wv] = val; red[4 + wv] = cv; }
    __syncthreads();
    if (t == 0) {
        sums[c] = red[0] + red[1] + red[2] + red[3];
        cnts[c] = red[4] + red[5] + red[6] + red[7];
    }
}

// K9: scalar epilogue
__global__ void k_final(const float* __restrict__ sums,
                        const float* __restrict__ cnts,
                        float* __restrict__ out)
{
    if (threadIdx.x == 0 && blockIdx.x == 0) {
        float total = 0.f, cnt = 0.f;
        for (int c = 0; c < 8; ++c) { total += sums[c]; cnt += cnts[c]; }
        out[0] = (cnt > 0.f) ? (1.0f - total / fmaxf(cnt, 1.0f)) : 1.0f;
    }
}

extern "C" void kernel_launch(void* const* d_in, const int* in_sizes, int n_in,
                              void* d_out, int out_size, void* d_ws, size_t ws_size,
                              hipStream_t stream)
{
    if (ws_size < WS_NEED) return;
    const float* clean = (const float*)d_in[0];
    const float* patch = (const float*)d_in[1];
    float* out = (float*)d_out;
    char* ws = (char*)d_ws;

    u64*    keys = (u64*)(ws + OFF_KEYS);
    u64*    mask = (u64*)(ws + OFF_KEYS);   // reuses keys region after k_sort
    int*    hist = (int*)(ws + OFF_HIST);
    int*    tbin = (int*)(ws + OFF_TBIN);
    int*    ccnt = (int*)(ws + OFF_CCNT);
    float*  sums = (float*)(ws + OFF_SUMS);
    float*  cnts = (float*)(ws + OFF_CNTS);
    u64*    cand = (u64*)(ws + OFF_CAND);
    float*  pmax = (float*)(ws + OFF_CAND); // reuses cand region after k_sort
    u64*    sel  = (u64*)(ws + OFF_SEL);
    float4* boxes = (float4*)(ws + OFF_BOX);
    int*    cls  = (int*)(ws + OFF_CLS);
    u64*    rinit = (u64*)(ws + OFF_RINIT);
    int*    keep = (int*)(ws + OFF_KEEP);

    hipMemsetAsync(ws + OFF_HIST, 0, ZERO_BYTES, stream);

    k_score<<<(NIMG * SCHUNKS) / 2, 128, 0, stream>>>(clean, patch, keys);
    k_hist<<<dim3(NIMG, 16), 256, 0, stream>>>(keys, hist);
    k_thresh<<<NIMG, 1024, 0, stream>>>(hist, tbin);
    k_compact<<<dim3(NIMG, 16), 256, 0, stream>>>(keys, tbin, ccnt, cand);
    k_sort<<<NIMG, 1024, 0, stream>>>(cand, ccnt, sel);
    k_gather<<<NIMG, 1024, 0, stream>>>(clean, patch, sel, boxes, cls, rinit);
    k_nms_mask<<<dim3(NIMG, 16), 1024, 0, stream>>>(boxes, cls, mask);
    k_nms_scan<<<NIMG, 1024, 131072, stream>>>(mask, rinit, keep);
    k_match_partial<<<dim3(8, 16), 256, 0, stream>>>(boxes, cls, keep, pmax);
    k_match_reduce<<<8, 256, 0, stream>>>(pmax, keep, sums, cnts);
    k_final<<<1, 64, 0, stream>>>(sums, cnts, out);
}

// Round 6
// 176.389 us; speedup vs baseline: 3.2562x; 1.2441x over previous
//
#include <hip/hip_runtime.h>

#define N_ANCH 25200
#define NCLS   80
#define ROW    85
#define NIMG   16
#define KMAX   1024
#define NBINS  4096
#define CAND_CAP 4096
#define SROWS   48           // rows per wave in k_score (25200 = 525*48)
#define SCHUNKS 525
#define SFLOATS (SROWS*ROW)  // 4080 floats = 16320 B per wave
#define PCHUNK 64            // patch boxes per match block
#define CCNT_STRIDE 16       // ints; one 64B line per image counter

typedef unsigned long long u64;
typedef unsigned int u32;

// ---------------- ws layout (bytes) ----------------
#define OFF_KEYS 0ull                      // 16*25200*8 = 3,225,600 ; reused as NMS mask (2 MB) after k_sort
#define OFF_HIST 3225600ull                // 16*4096*4  =   262,144
#define OFF_TBIN 3487744ull                // 16*4 = 64
#define OFF_CCNT 3487808ull                // 16*64 = 1,024 (padded: 1 line/counter)
#define OFF_SUMS 3488832ull                // 8*4 = 32
#define OFF_CNTS 3488864ull                // 8*4 = 32
#define OFF_CAND 3488896ull                // 16*4096*8 = 524,288 ; reused as pmax (128 KB) after k_sort
#define OFF_SEL  4013184ull                // 16*1024*8 = 131,072
#define OFF_BOX  4144256ull                // 16*1024*16 = 262,144
#define OFF_CLS  4406400ull                // 16*1024*4 = 65,536
#define OFF_RINIT 4471936ull               // 16*16*8 = 2,048 (initial removal bitmask)
#define OFF_KEEP 4473984ull                // 16*1024*4 = 65,536
#define WS_NEED  4539520ull
#define ZERO_BYTES (262144ull + 64 + 1024 + 32 + 32)   // hist..cnts contiguous

__device__ __forceinline__ int key_bin(u64 key) {
    u32 hi = (u32)(key >> 32);
    if (hi == 0u) return 0;
    float conf = __uint_as_float(hi - 0x40000000u);
    int b = 1 + (int)(conf * 4093.0f);
    return b > 4094 ? 4094 : b;
}

__device__ __forceinline__ u64 shfl64(u64 v, int src) {
    int lo = __shfl((int)(u32)(v & 0xffffffffull), src, 64);
    int hi = __shfl((int)(u32)(v >> 32), src, 64);
    return ((u64)(u32)hi << 32) | (u64)(u32)lo;
}

// K1: per-entry conf/cls/validity -> 64-bit sort key.
// Staging via global_load_lds DMA (fire-and-forget, ~16 KB in flight per wave),
// wave-local vmcnt wait (no barriers). 48 rows/wave, 25200 = 525*48 exactly.
__global__ __launch_bounds__(128) void k_score(const float* __restrict__ clean,
                                               const float* __restrict__ patch,
                                               u64* __restrict__ keys)
{
    __shared__ float lds[2][SFLOATS];    // 32,640 B -> 5 blocks/CU (10 waves/CU)
    const int wv   = threadIdx.x >> 6;
    const int lane = threadIdx.x & 63;
    const int wave_id = blockIdx.x * 2 + wv;
    const int b     = wave_id / SCHUNKS;
    const int chunk = wave_id - b * SCHUNKS;
    const float* src = (b < 8) ? (clean + (size_t)b * N_ANCH * ROW)
                               : (patch + (size_t)(b - 8) * N_ANCH * ROW);
    const int base = chunk * SROWS;
    const float* g = src + (size_t)base * ROW;
    float* lbuf = &lds[wv][0];
    #pragma unroll
    for (int t = 0; t < 15; ++t)
        __builtin_amdgcn_global_load_lds(
            (const __attribute__((address_space(1))) void*)(g + t * 256 + lane * 4),
            (__attribute__((address_space(3))) void*)(lbuf + t * 256), 16, 0, 0);
    if (lane < 60) {
        const float4 v = *(const float4*)(g + 3840 + lane * 4);
        *(float4*)(lbuf + 3840 + lane * 4) = v;
    }
    asm volatile("s_waitcnt vmcnt(0) lgkmcnt(0)" ::: "memory");
    __builtin_amdgcn_sched_barrier(0);
    if (lane < SROWS) {
        const float* p = lbuf + lane * ROW;
        const float obj = p[4];
        float best = -1.0f; int bc = 0;
        #pragma unroll 8
        for (int d = 0; d < NCLS; ++d) {
            float s = p[5 + d] * obj;
            if (s > best) { best = s; bc = d; }
        }
        const float th = (b < 8) ? 0.25f : 0.001f;
        const bool valid = (obj > th) && (best > th);
        const u32 hi = valid ? (__float_as_uint(best) + 0x40000000u) : 0u;
        const u32 nbar = 32767u - (u32)(base + lane);
        keys[(size_t)b * N_ANCH + base + lane] =
            ((u64)hi << 32) | ((u64)nbar << 8) | (u64)(u32)bc;
    }
}

// K2: per-image histogram of conf bins (LDS hist; flush atomics don't return -> pipelined)
__global__ __launch_bounds__(256) void k_hist(const u64* __restrict__ keys,
                                              int* __restrict__ hist)
{
    __shared__ int h[NBINS];
    const int b = blockIdx.x;
    for (int i = threadIdx.x; i < NBINS; i += 256) h[i] = 0;
    __syncthreads();
    const int start = blockIdx.y * 1575;
    const u64* kp = keys + (size_t)b * N_ANCH;
    for (int i = start + threadIdx.x; i < start + 1575; i += 256)
        atomicAdd(&h[key_bin(kp[i])], 1);
    __syncthreads();
    for (int i = threadIdx.x; i < NBINS; i += 256)
        if (h[i]) atomicAdd(&hist[b * NBINS + i], h[i]);
}

// K3: per-image suffix-scan over bins -> threshold bin
__global__ __launch_bounds__(1024) void k_thresh(const int* __restrict__ hist,
                                                 int* __restrict__ tbin)
{
    __shared__ int arr[1024];
    const int b = blockIdx.x;
    const int t = threadIdx.x;
    int hh[4];
    hh[0] = hist[b * NBINS + 4 * t + 0];
    hh[1] = hist[b * NBINS + 4 * t + 1];
    hh[2] = hist[b * NBINS + 4 * t + 2];
    hh[3] = hist[b * NBINS + 4 * t + 3];
    const int r = hh[0] + hh[1] + hh[2] + hh[3];
    arr[t] = r;
    __syncthreads();
    for (int off = 1; off < 1024; off <<= 1) {
        int v = (t + off < 1024) ? arr[t + off] : 0;
        __syncthreads();
        arr[t] += v;
        __syncthreads();
    }
    const int K = (b < 8) ? 256 : 1024;
    int cb = arr[t] - r;
    for (int d = 3; d >= 0; --d) {
        int ca = cb + hh[d];
        if (cb < K && ca >= K) tbin[b] = 4 * t + d;
        cb = ca;
    }
}

// K4: compact candidates with bin >= T. Wave-aggregated atomics:
// one returning atomicAdd per wave-iteration (was one per candidate);
// candidate order is irrelevant (k_sort orders by full unique key).
__global__ __launch_bounds__(256) void k_compact(const u64* __restrict__ keys,
                                                 const int* __restrict__ tbin,
                                                 int* __restrict__ ccnt,
                                                 u64* __restrict__ cand)
{
    const int b = blockIdx.x;
    const int T = tbin[b];
    const u64* kp = keys + (size_t)b * N_ANCH;
    const int start = blockIdx.y * 1575;
    const int lane = threadIdx.x & 63;
    #pragma unroll
    for (int it = 0; it < 7; ++it) {
        const int off = it * 256 + threadIdx.x;          // 0..1791
        const bool in = off < 1575;
        const u64 key = in ? kp[start + off] : 0ull;
        const bool cnd = in && (key_bin(key) >= T);
        const u64 bal = __ballot(cnd);
        if (bal) {
            int base = 0;
            if (lane == 0) base = atomicAdd(&ccnt[b * CCNT_STRIDE], __popcll(bal));
            base = __shfl(base, 0, 64);
            if (cnd) {
                const int pos = base + __popcll(bal & ((1ull << lane) - 1ull));
                if (pos < CAND_CAP) cand[(size_t)b * CAND_CAP + pos] = key;
            }
        }
    }
}

// K5: per-image bitonic sort (descending) of candidates, emit top-K keys
__global__ __launch_bounds__(1024) void k_sort(const u64* __restrict__ cand,
                                               const int* __restrict__ ccnt,
                                               u64* __restrict__ sel)
{
    __shared__ u64 sk[CAND_CAP];   // 32 KB
    const int b = blockIdx.x;
    const int C = min(ccnt[b * CCNT_STRIDE], CAND_CAP);
    const int t = threadIdx.x;
    #pragma unroll
    for (int p = 0; p < CAND_CAP / 1024; ++p) {
        int i = p * 1024 + t;
        sk[i] = (i < C) ? cand[(size_t)b * CAND_CAP + i] : 0ull;
    }
    __syncthreads();
    for (int k = 2; k <= CAND_CAP; k <<= 1) {
        for (int j = k >> 1; j > 0; j >>= 1) {
            #pragma unroll
            for (int p = 0; p < CAND_CAP / 1024; ++p) {
                int i = p * 1024 + t;
                int ixj = i ^ j;
                if (ixj > i) {
                    u64 a = sk[i], c = sk[ixj];
                    bool descSeg = ((i & k) == 0);
                    bool sw = descSeg ? (a < c) : (a > c);
                    if (sw) { sk[i] = c; sk[ixj] = a; }
                }
            }
            __syncthreads();
        }
    }
    const int K = (b < 8) ? 256 : 1024;
    if (t < K) sel[b * KMAX + t] = sk[t];
}

// K6: decode keys, gather boxes (xywh->xyxy), cls; ballot initial removal mask
__global__ __launch_bounds__(1024) void k_gather(const float* __restrict__ clean,
                                                 const float* __restrict__ patch,
                                                 const u64* __restrict__ sel,
                                                 float4* __restrict__ boxes,
                                                 int* __restrict__ cls,
                                                 u64* __restrict__ rinit)
{
    const int b = blockIdx.x;
    const int t = threadIdx.x;
    const int K = (b < 8) ? 256 : 1024;
    const u64 key = (t < K) ? sel[b * KMAX + t] : 0ull;
    const u32 hi = (u32)(key >> 32);
    const bool valid = (t < K) && (hi != 0u);
    u64 bal = __ballot(valid);
    if ((t & 63) == 0) rinit[b * 16 + (t >> 6)] = ~bal;
    if (t >= K) return;
    const int n = 32767 - (int)((key >> 8) & 0x7FFFu);
    const int c = (int)(key & 0x7Fu);
    const float* src = ((b < 8) ? (clean + (size_t)b * N_ANCH * ROW)
                                : (patch + (size_t)(b - 8) * N_ANCH * ROW)) + (size_t)n * ROW;
    const float x = src[0], y = src[1], w = src[2], h = src[3];
    boxes[b * KMAX + t] = make_float4(x - w * 0.5f, y - h * 0.5f, x + w * 0.5f, y + h * 0.5f);
    cls[b * KMAX + t] = c;
}

// K7a: parallel suppression-mask build. Wave = one 64-bit word column across 64 rows.
__global__ __launch_bounds__(1024) void k_nms_mask(const float4* __restrict__ boxes,
                                                   const int* __restrict__ cls,
                                                   u64* __restrict__ mask)
{
    __shared__ float4 bx[KMAX];
    __shared__ float ar[KMAX];
    const int b = blockIdx.x;
    const int K = (b < 8) ? 256 : 1024;
    const int row0 = blockIdx.y * 64;
    if (row0 >= K) return;                  // block-uniform
    const int t = threadIdx.x;
    for (int i = t; i < K; i += 1024) {
        float4 v = boxes[b * KMAX + i];
        float off = (float)cls[b * KMAX + i] * 4096.0f;
        v.x += off; v.y += off; v.z += off; v.w += off;
        bx[i] = v;
        ar[i] = (v.z - v.x) * (v.w - v.y);
    }
    __syncthreads();
    const int w   = t >> 6;                 // word column (wave-uniform)
    const int row = row0 + (t & 63);        // lane-distinct row
    u64* dst = mask + ((size_t)b * KMAX + row) * 16 + w;
    if (((w << 6) + 63) <= row0 && row0 > 0) { *dst = 0ull; return; }   // all j <= min row: zero word
    const float4 bi = bx[row];
    const float ai = ar[row];
    const int jbase = w << 6;
    u64 m = 0;
    #pragma unroll 8
    for (int k = 0; k < 64; ++k) {
        const int j = jbase + k;            // wave-uniform -> LDS broadcast
        const float4 bj = bx[j];
        const float ax = fmaxf(bi.x, bj.x), ay = fmaxf(bi.y, bj.y);
        const float bx2 = fminf(bi.z, bj.z), by2 = fminf(bi.w, bj.w);
        const float iw = fmaxf(bx2 - ax, 0.f), ih = fmaxf(by2 - ay, 0.f);
        const float inter = iw * ih;
        const float iou = inter / (ai + ar[j] - inter);
        if (j > row && iou > 0.45f) m |= (1ull << k);
    }
    *dst = m;
}

// K7b: serial scan, one block per image. Whole mask staged to LDS first (bulk
// coalesced read), then wave 0 scans from LDS. Zero barriers inside the scan.
__global__ __launch_bounds__(1024) void k_nms_scan(const u64* __restrict__ mask,
                                                   const u64* __restrict__ rinit,
                                                   int* __restrict__ keep)
{
    extern __shared__ u64 smask[];          // 128 KB (patch) / 16 KB (clean)
    const int b = blockIdx.x;
    const int K = (b < 8) ? 256 : 1024;
    const int W = K >> 6;
    const int t = threadIdx.x;
    {
        const float4* s4 = (const float4*)(mask + (size_t)b * KMAX * 16);
        float4* d4 = (float4*)smask;
        const int n4 = (K * 16) >> 1;       // 2 u64 per float4
        for (int i = t; i < n4; i += 1024) d4[i] = s4[i];
    }
    __syncthreads();
    if (t >= 64) return;
    const int lane = t;
    const int wl = lane & 15;               // lanes 16+ mirror words 0..15 (values unused)
    u64 w_remv = rinit[b * 16 + wl];
    #pragma unroll 4
    for (int i = 0; i < K; i += 4) {
        const u64* p = smask + (size_t)i * 16 + wl;
        const u64 m0 = p[0], m1 = p[16], m2 = p[32], m3 = p[48];
        const int owner = i >> 6;
        const u64 ow  = shfl64(w_remv, owner);
        const u64 m0o = shfl64(m0, owner);
        const u64 m1o = shfl64(m1, owner);
        const u64 m2o = shfl64(m2, owner);
        const int b0 = i & 63;
        const bool k0 = !((ow >> b0) & 1);
        u64 acc = k0 ? m0o : 0ull;
        const bool k1 = !(((ow | acc) >> (b0 + 1)) & 1);
        if (k1) acc |= m1o;
        const bool k2 = !(((ow | acc) >> (b0 + 2)) & 1);
        if (k2) acc |= m2o;
        const bool k3 = !(((ow | acc) >> (b0 + 3)) & 1);
        w_remv |= (k0 ? m0 : 0ull) | (k1 ? m1 : 0ull) | (k2 ? m2 : 0ull) | (k3 ? m3 : 0ull);
    }
    if (lane < W) {
        for (int k = 0; k < 64; ++k)
            keep[b * KMAX + lane * 64 + k] = (int)(((w_remv >> k) & 1) ^ 1ull);
    }
}

// K8a: partial max IoU: block = (clean image, patch chunk of 64). Branchless inner loop.
__global__ __launch_bounds__(256) void k_match_partial(const float4* __restrict__ boxes,
                                                       const int* __restrict__ cls,
                                                       const int* __restrict__ keep,
                                                       float* __restrict__ pmax)
{
    __shared__ float4 pb[PCHUNK];
    __shared__ float par[PCHUNK];
    __shared__ int pcls[PCHUNK];
    const int c = blockIdx.x;        // clean image 0..7
    const int p = blockIdx.y;        // patch chunk 0..15
    const int bp = 8 + c;
    const int t = threadIdx.x;
    if (t < PCHUNK) {
        const int i = p * PCHUNK + t;
        const float4 v = boxes[bp * KMAX + i];
        pb[t] = v;
        par[t] = (v.z - v.x) * (v.w - v.y);
        pcls[t] = keep[bp * KMAX + i] ? cls[bp * KMAX + i] : -1;   // fold keep into class
    }
    __syncthreads();
    const float4 bc = boxes[c * KMAX + t];
    const int cc = cls[c * KMAX + t];
    const float area_c = (bc.z - bc.x) * (bc.w - bc.y);
    float tm = 0.f;
    #pragma unroll 8
    for (int i = 0; i < PCHUNK; ++i) {
        const float4 bi = pb[i];
        const float ax = fmaxf(bi.x, bc.x), ay = fmaxf(bi.y, bc.y);
        const float bx2 = fminf(bi.z, bc.z), by2 = fminf(bi.w, bc.w);
        const float iw = fmaxf(bx2 - ax, 0.f), ih = fmaxf(by2 - ay, 0.f);
        const float inter = iw * ih;
        const float iou = inter / (par[i] + area_c - inter);
        tm = fmaxf(tm, (pcls[i] == cc) ? iou : 0.f);
    }
    pmax[(c * 16 + p) * 256 + t] = tm;
}

// K8b: reduce over chunks, mask by clean keep, sum
__global__ __launch_bounds__(256) void k_match_reduce(const float* __restrict__ pmax,
                                                      const int* __restrict__ keep,
                                                      float* __restrict__ sums,
                                                      float* __restrict__ cnts)
{
    __shared__ float red[8];
    const int c = blockIdx.x;
    const int t = threadIdx.x;
    float tm = 0.f;
    #pragma unroll
    for (int p = 0; p < 16; ++p)
        tm = fmaxf(tm, pmax[(c * 16 + p) * 256 + t]);
    const int kc = keep[c * KMAX + t];
    float val = kc ? tm : 0.f;
    float cv  = kc ? 1.f : 0.f;
    for (int off = 32; off > 0; off >>= 1) {
        val += __shfl_down(val, off);
        cv  += __shfl_down(cv, off);
    }
    const int wv = t >> 6, lane = t & 63;
    if (lane == 0) { red[wv] = val; red[4 + wv] = cv; }
    __syncthreads();
    if (t == 0) {
        sums[c] = red[0] + red[1] + red[2] + red[3];
        cnts[c] = red[4] + red[5] + red[6] + red[7];
    }
}

// K9: scalar epilogue
__global__ void k_final(const float* __restrict__ sums,
                        const float* __restrict__ cnts,
                        float* __restrict__ out)
{
    if (threadIdx.x == 0 && blockIdx.x == 0) {
        float total = 0.f, cnt = 0.f;
        for (int c = 0; c < 8; ++c) { total += sums[c]; cnt += cnts[c]; }
        out[0] = (cnt > 0.f) ? (1.0f - total / fmaxf(cnt, 1.0f)) : 1.0f;
    }
}

extern "C" void kernel_launch(void* const* d_in, const int* in_sizes, int n_in,
                              void* d_out, int out_size, void* d_ws, size_t ws_size,
                              hipStream_t stream)
{
    if (ws_size < WS_NEED) return;
    const float* clean = (const float*)d_in[0];
    const float* patch = (const float*)d_in[1];
    float* out = (float*)d_out;
    char* ws = (char*)d_ws;

    u64*    keys = (u64*)(ws + OFF_KEYS);
    u64*    mask = (u64*)(ws + OFF_KEYS);   // reuses keys region after k_sort
    int*    hist = (int*)(ws + OFF_HIST);
    int*    tbin = (int*)(ws + OFF_TBIN);
    int*    ccnt = (int*)(ws + OFF_CCNT);
    float*  sums = (float*)(ws + OFF_SUMS);
    float*  cnts = (float*)(ws + OFF_CNTS);
    u64*    cand = (u64*)(ws + OFF_CAND);
    float*  pmax = (float*)(ws + OFF_CAND); // reuses cand region after k_sort
    u64*    sel  = (u64*)(ws + OFF_SEL);
    float4* boxes = (float4*)(ws + OFF_BOX);
    int*    cls  = (int*)(ws + OFF_CLS);
    u64*    rinit = (u64*)(ws + OFF_RINIT);
    int*    keep = (int*)(ws + OFF_KEEP);

    hipMemsetAsync(ws + OFF_HIST, 0, ZERO_BYTES, stream);

    k_score<<<(NIMG * SCHUNKS) / 2, 128, 0, stream>>>(clean, patch, keys);
    k_hist<<<dim3(NIMG, 16), 256, 0, stream>>>(keys, hist);
    k_thresh<<<NIMG, 1024, 0, stream>>>(hist, tbin);
    k_compact<<<dim3(NIMG, 16), 256, 0, stream>>>(keys, tbin, ccnt, cand);
    k_sort<<<NIMG, 1024, 0, stream>>>(cand, ccnt, sel);
    k_gather<<<NIMG, 1024, 0, stream>>>(clean, patch, sel, boxes, cls, rinit);
    k_nms_mask<<<dim3(NIMG, 16), 1024, 0, stream>>>(boxes, cls, mask);
    k_nms_scan<<<NIMG, 1024, 131072, stream>>>(mask, rinit, keep);
    k_match_partial<<<dim3(8, 16), 256, 0, stream>>>(boxes, cls, keep, pmax);
    k_match_reduce<<<8, 256, 0, stream>>>(pmax, keep, sums, cnts);
    k_final<<<1, 64, 0, stream>>>(sums, cnts, out);
}

// Round 7
// 171.430 us; speedup vs baseline: 3.3504x; 1.0289x over previous
//
#include <hip/hip_runtime.h>

#define N_ANCH 25200
#define NCLS   80
#define ROW    85
#define NIMG   16
#define KMAX   1024
#define NBINS  4096
#define CAND_CAP 4096
#define SROWS   20           // rows per wave in k_score (25200 = 1260*20)
#define SCHUNKS 1260
#define SFLOATS 1792         // padded to 7 x 1KB DMA coverage (20*85=1700 used)
#define PCHUNK 64            // patch boxes per match block
#define CCNT_STRIDE 16       // ints; one 64B line per image counter

typedef unsigned long long u64;
typedef unsigned int u32;

// ---------------- ws layout (bytes) ----------------
#define OFF_KEYS 0ull                      // 16*25200*8 = 3,225,600 ; reused as NMS mask (2 MB) after k_sort
#define OFF_HIST 3225600ull                // 16*4096*4  =   262,144 ; reused as diag (128 KB) after k_thresh
#define OFF_TBIN 3487744ull                // 16*4 = 64
#define OFF_CCNT 3487808ull                // 16*64 = 1,024 (padded: 1 line/counter)
#define OFF_SUMS 3488832ull                // 8*4 = 32
#define OFF_CNTS 3488864ull                // 8*4 = 32
#define OFF_CAND 3488896ull                // 16*4096*8 = 524,288 ; reused as pmax (128 KB) after k_sort
#define OFF_SEL  4013184ull                // 16*1024*8 = 131,072
#define OFF_BOX  4144256ull                // 16*1024*16 = 262,144
#define OFF_CLS  4406400ull                // 16*1024*4 = 65,536
#define OFF_RINIT 4471936ull               // 16*16*8 = 2,048 (initial removal bitmask)
#define OFF_KEEP 4473984ull                // 16*1024*4 = 65,536
#define WS_NEED  4539520ull
#define ZERO_BYTES (262144ull + 64 + 1024 + 32 + 32)   // hist..cnts contiguous

__device__ __forceinline__ int key_bin(u64 key) {
    u32 hi = (u32)(key >> 32);
    if (hi == 0u) return 0;
    float conf = __uint_as_float(hi - 0x40000000u);
    int b = 1 + (int)(conf * 4093.0f);
    return b > 4094 ? 4094 : b;
}

__device__ __forceinline__ u64 readlane64(u64 v, int src) {
    u32 lo = (u32)__builtin_amdgcn_readlane((int)(u32)(v & 0xffffffffull), src);
    u32 hi = (u32)__builtin_amdgcn_readlane((int)(u32)(v >> 32), src);
    return ((u64)hi << 32) | (u64)lo;
}

// K1: per-entry conf/cls/validity -> 64-bit sort key.
// 20 rows/wave, 7 x 1KB global_load_lds DMA per chunk (7th per-lane clamped
// to image end), wave-local vmcnt wait, no barriers. LDS 14 KB/block ->
// 11 blocks/CU = 22 waves/CU (69% occupancy) to hide HBM/L3 latency.
__global__ __launch_bounds__(128) void k_score(const float* __restrict__ clean,
                                               const float* __restrict__ patch,
                                               u64* __restrict__ keys)
{
    __shared__ float lds[2][SFLOATS];    // 14,336 B/block
    const int wv   = threadIdx.x >> 6;
    const int lane = threadIdx.x & 63;
    const int wave_id = blockIdx.x * 2 + wv;
    const int b     = wave_id / SCHUNKS;
    const int chunk = wave_id - b * SCHUNKS;
    const float* src = (b < 8) ? (clean + (size_t)b * N_ANCH * ROW)
                               : (patch + (size_t)(b - 8) * N_ANCH * ROW);
    const int base = chunk * SROWS;
    const float* g = src + (size_t)base * ROW;
    float* lbuf = &lds[wv][0];
    #pragma unroll
    for (int t = 0; t < 6; ++t)
        __builtin_amdgcn_global_load_lds(
            (const __attribute__((address_space(1))) void*)(g + t * 256 + lane * 4),
            (__attribute__((address_space(3))) void*)(lbuf + t * 256), 16, 0, 0);
    // 7th KB: clamp per-lane src to last valid float4 of this image (overreads
    // land in lds[1700..1792) which compute never touches)
    {
        const float* s7 = g + 1536 + lane * 4;
        const float* lim = src + (size_t)N_ANCH * ROW - 4;
        if (s7 > lim) s7 = lim;
        __builtin_amdgcn_global_load_lds(
            (const __attribute__((address_space(1))) void*)s7,
            (__attribute__((address_space(3))) void*)(lbuf + 1536), 16, 0, 0);
    }
    asm volatile("s_waitcnt vmcnt(0)" ::: "memory");
    __builtin_amdgcn_sched_barrier(0);
    if (lane < SROWS) {
        const float* p = lbuf + lane * ROW;
        const float obj = p[4];
        float best = -1.0f; int bc = 0;
        #pragma unroll 8
        for (int d = 0; d < NCLS; ++d) {
            float s = p[5 + d] * obj;
            if (s > best) { best = s; bc = d; }
        }
        const float th = (b < 8) ? 0.25f : 0.001f;
        const bool valid = (obj > th) && (best > th);
        const u32 hi = valid ? (__float_as_uint(best) + 0x40000000u) : 0u;
        const u32 nbar = 32767u - (u32)(base + lane);
        keys[(size_t)b * N_ANCH + base + lane] =
            ((u64)hi << 32) | ((u64)nbar << 8) | (u64)(u32)bc;
    }
}

// K2: per-image histogram of conf bins
__global__ __launch_bounds__(256) void k_hist(const u64* __restrict__ keys,
                                              int* __restrict__ hist)
{
    __shared__ int h[NBINS];
    const int b = blockIdx.x;
    for (int i = threadIdx.x; i < NBINS; i += 256) h[i] = 0;
    __syncthreads();
    const int start = blockIdx.y * 1575;
    const u64* kp = keys + (size_t)b * N_ANCH;
    for (int i = start + threadIdx.x; i < start + 1575; i += 256)
        atomicAdd(&h[key_bin(kp[i])], 1);
    __syncthreads();
    for (int i = threadIdx.x; i < NBINS; i += 256)
        if (h[i]) atomicAdd(&hist[b * NBINS + i], h[i]);
}

// K3: per-image suffix-scan over bins -> threshold bin
__global__ __launch_bounds__(1024) void k_thresh(const int* __restrict__ hist,
                                                 int* __restrict__ tbin)
{
    __shared__ int arr[1024];
    const int b = blockIdx.x;
    const int t = threadIdx.x;
    int hh[4];
    hh[0] = hist[b * NBINS + 4 * t + 0];
    hh[1] = hist[b * NBINS + 4 * t + 1];
    hh[2] = hist[b * NBINS + 4 * t + 2];
    hh[3] = hist[b * NBINS + 4 * t + 3];
    const int r = hh[0] + hh[1] + hh[2] + hh[3];
    arr[t] = r;
    __syncthreads();
    for (int off = 1; off < 1024; off <<= 1) {
        int v = (t + off < 1024) ? arr[t + off] : 0;
        __syncthreads();
        arr[t] += v;
        __syncthreads();
    }
    const int K = (b < 8) ? 256 : 1024;
    int cb = arr[t] - r;
    for (int d = 3; d >= 0; --d) {
        int ca = cb + hh[d];
        if (cb < K && ca >= K) tbin[b] = 4 * t + d;
        cb = ca;
    }
}

// K4: compact candidates with bin >= T (wave-aggregated atomics)
__global__ __launch_bounds__(256) void k_compact(const u64* __restrict__ keys,
                                                 const int* __restrict__ tbin,
                                                 int* __restrict__ ccnt,
                                                 u64* __restrict__ cand)
{
    const int b = blockIdx.x;
    const int T = tbin[b];
    const u64* kp = keys + (size_t)b * N_ANCH;
    const int start = blockIdx.y * 1575;
    const int lane = threadIdx.x & 63;
    #pragma unroll
    for (int it = 0; it < 7; ++it) {
        const int off = it * 256 + threadIdx.x;          // 0..1791
        const bool in = off < 1575;
        const u64 key = in ? kp[start + off] : 0ull;
        const bool cnd = in && (key_bin(key) >= T);
        const u64 bal = __ballot(cnd);
        if (bal) {
            int base = 0;
            if (lane == 0) base = atomicAdd(&ccnt[b * CCNT_STRIDE], __popcll(bal));
            base = __shfl(base, 0, 64);
            if (cnd) {
                const int pos = base + __popcll(bal & ((1ull << lane) - 1ull));
                if (pos < CAND_CAP) cand[(size_t)b * CAND_CAP + pos] = key;
            }
        }
    }
}

// K5: per-image bitonic sort (descending) of candidates, emit top-K keys
__global__ __launch_bounds__(1024) void k_sort(const u64* __restrict__ cand,
                                               const int* __restrict__ ccnt,
                                               u64* __restrict__ sel)
{
    __shared__ u64 sk[CAND_CAP];   // 32 KB
    const int b = blockIdx.x;
    const int C = min(ccnt[b * CCNT_STRIDE], CAND_CAP);
    const int t = threadIdx.x;
    #pragma unroll
    for (int p = 0; p < CAND_CAP / 1024; ++p) {
        int i = p * 1024 + t;
        sk[i] = (i < C) ? cand[(size_t)b * CAND_CAP + i] : 0ull;
    }
    __syncthreads();
    for (int k = 2; k <= CAND_CAP; k <<= 1) {
        for (int j = k >> 1; j > 0; j >>= 1) {
            #pragma unroll
            for (int p = 0; p < CAND_CAP / 1024; ++p) {
                int i = p * 1024 + t;
                int ixj = i ^ j;
                if (ixj > i) {
                    u64 a = sk[i], c = sk[ixj];
                    bool descSeg = ((i & k) == 0);
                    bool sw = descSeg ? (a < c) : (a > c);
                    if (sw) { sk[i] = c; sk[ixj] = a; }
                }
            }
            __syncthreads();
        }
    }
    const int K = (b < 8) ? 256 : 1024;
    if (t < K) sel[b * KMAX + t] = sk[t];
}

// K6: decode keys, gather boxes (xywh->xyxy), cls; ballot initial removal mask
__global__ __launch_bounds__(1024) void k_gather(const float* __restrict__ clean,
                                                 const float* __restrict__ patch,
                                                 const u64* __restrict__ sel,
                                                 float4* __restrict__ boxes,
                                                 int* __restrict__ cls,
                                                 u64* __restrict__ rinit)
{
    const int b = blockIdx.x;
    const int t = threadIdx.x;
    const int K = (b < 8) ? 256 : 1024;
    const u64 key = (t < K) ? sel[b * KMAX + t] : 0ull;
    const u32 hi = (u32)(key >> 32);
    const bool valid = (t < K) && (hi != 0u);
    u64 bal = __ballot(valid);
    if ((t & 63) == 0) rinit[b * 16 + (t >> 6)] = ~bal;
    if (t >= K) return;
    const int n = 32767 - (int)((key >> 8) & 0x7FFFu);
    const int c = (int)(key & 0x7Fu);
    const float* src = ((b < 8) ? (clean + (size_t)b * N_ANCH * ROW)
                                : (patch + (size_t)(b - 8) * N_ANCH * ROW)) + (size_t)n * ROW;
    const float x = src[0], y = src[1], w = src[2], h = src[3];
    boxes[b * KMAX + t] = make_float4(x - w * 0.5f, y - h * 0.5f, x + w * 0.5f, y + h * 0.5f);
    cls[b * KMAX + t] = c;
}

// K7a: parallel suppression-mask build. Wave = one 64-bit word column across 64 rows.
// Also emits the per-row DIAGONAL word (intra-group suppression) contiguously.
__global__ __launch_bounds__(1024) void k_nms_mask(const float4* __restrict__ boxes,
                                                   const int* __restrict__ cls,
                                                   u64* __restrict__ mask,
                                                   u64* __restrict__ diag)
{
    __shared__ float4 bx[KMAX];
    __shared__ float ar[KMAX];
    const int b = blockIdx.x;
    const int K = (b < 8) ? 256 : 1024;
    const int row0 = blockIdx.y * 64;
    if (row0 >= K) return;                  // block-uniform
    const int t = threadIdx.x;
    for (int i = t; i < K; i += 1024) {
        float4 v = boxes[b * KMAX + i];
        float off = (float)cls[b * KMAX + i] * 4096.0f;
        v.x += off; v.y += off; v.z += off; v.w += off;
        bx[i] = v;
        ar[i] = (v.z - v.x) * (v.w - v.y);
    }
    __syncthreads();
    const int w   = t >> 6;                 // word column (wave-uniform)
    const int row = row0 + (t & 63);        // lane-distinct row
    u64* dst = mask + ((size_t)b * KMAX + row) * 16 + w;
    if (((w << 6) + 63) <= row0 && row0 > 0) { *dst = 0ull; return; }   // all j <= min row: zero word
    const float4 bi = bx[row];
    const float ai = ar[row];
    const int jbase = w << 6;
    u64 m = 0;
    #pragma unroll 8
    for (int k = 0; k < 64; ++k) {
        const int j = jbase + k;            // wave-uniform -> LDS broadcast
        const float4 bj = bx[j];
        const float ax = fmaxf(bi.x, bj.x), ay = fmaxf(bi.y, bj.y);
        const float bx2 = fminf(bi.z, bj.z), by2 = fminf(bi.w, bj.w);
        const float iw = fmaxf(bx2 - ax, 0.f), ih = fmaxf(by2 - ay, 0.f);
        const float inter = iw * ih;
        const float iou = inter / (ai + ar[j] - inter);
        if (j > row && iou > 0.45f) m |= (1ull << k);
    }
    *dst = m;
    if (w == (row0 >> 6)) diag[(size_t)b * KMAX + row] = m;
}

// K7b: greedy scan, one block per image. Mask+diag staged to LDS; per 64-row
// group: (A) 64-step keep chain on wave-uniform SALU values (diag words via
// v_readlane -> SGPR; kept64 = ~o since mask is strictly upper-triangular),
// (B) apply all kept rows' mask words with pipelined unconditional ds_reads.
// No cross-lane ops on the critical chain (1 readlane64 per group).
__global__ __launch_bounds__(1024) void k_nms_scan(const u64* __restrict__ mask,
                                                   const u64* __restrict__ diag,
                                                   const u64* __restrict__ rinit,
                                                   int* __restrict__ keep)
{
    extern __shared__ u64 smem[];           // K*16 mask + K diag
    const int b = blockIdx.x;
    const int K = (b < 8) ? 256 : 1024;
    const int W = K >> 6;
    const int t = threadIdx.x;
    u64* smask = smem;
    u64* sdiag = smem + (size_t)K * 16;
    {
        const float4* s4 = (const float4*)(mask + (size_t)b * KMAX * 16);
        float4* d4 = (float4*)smask;
        const int n4 = (K * 16) >> 1;
        for (int i = t; i < n4; i += 1024) d4[i] = s4[i];
        const float4* s4d = (const float4*)(diag + (size_t)b * KMAX);
        float4* d4d = (float4*)sdiag;
        for (int i = t; i < (K >> 1); i += 1024) d4d[i] = s4d[i];
    }
    __syncthreads();
    if (t >= 64) return;
    const int lane = t;
    const int wl = lane & 15;
    u64 w_remv = rinit[b * 16 + wl];
    u64 ow = readlane64(w_remv, 0);
    u64 dj = sdiag[lane];                   // group 0 diag, lane j holds row j's word
    for (int g = 0; g < W; ++g) {
        const u32 dlo = (u32)(dj & 0xffffffffull);
        const u32 dhi = (u32)(dj >> 32);
        // Phase A: serial keep chain, wave-uniform (SALU)
        u64 o = ow;
        #pragma unroll
        for (int j = 0; j < 64; ++j) {
            const u64 ds = ((u64)(u32)__builtin_amdgcn_readlane((int)dhi, j) << 32)
                         |  (u64)(u32)__builtin_amdgcn_readlane((int)dlo, j);
            o |= (o & (1ull << j)) ? 0ull : ds;
        }
        const u64 kept = ~o;
        if (g + 1 < W) dj = sdiag[(g + 1) * 64 + lane];   // prefetch next group's diag
        // Phase B: w_remv |= OR over kept rows of their mask word wl
        const u64* mrow = smask + (size_t)g * 64 * 16 + wl;
        u64 a0 = 0, a1 = 0, a2 = 0, a3 = 0;
        #pragma unroll
        for (int j = 0; j < 64; j += 4) {
            const u64 m0 = mrow[(size_t)(j + 0) * 16];
            const u64 m1 = mrow[(size_t)(j + 1) * 16];
            const u64 m2 = mrow[(size_t)(j + 2) * 16];
            const u64 m3 = mrow[(size_t)(j + 3) * 16];
            a0 |= ((kept >> (j + 0)) & 1ull) ? m0 : 0ull;
            a1 |= ((kept >> (j + 1)) & 1ull) ? m1 : 0ull;
            a2 |= ((kept >> (j + 2)) & 1ull) ? m2 : 0ull;
            a3 |= ((kept >> (j + 3)) & 1ull) ? m3 : 0ull;
        }
        w_remv |= (a0 | a1) | (a2 | a3);
        if (g + 1 < W) ow = readlane64(w_remv, g + 1);
    }
    if (lane < W) {
        #pragma unroll
        for (int k = 0; k < 64; ++k)
            keep[b * KMAX + lane * 64 + k] = (int)(((w_remv >> k) & 1) ^ 1ull);
    }
}

// K8a: partial max IoU: block = (clean image, patch chunk of 64). Branchless inner loop.
__global__ __launch_bounds__(256) void k_match_partial(const float4* __restrict__ boxes,
                                                       const int* __restrict__ cls,
                                                       const int* __restrict__ keep,
                                                       float* __restrict__ pmax)
{
    __shared__ float4 pb[PCHUNK];
    __shared__ float par[PCHUNK];
    __shared__ int pcls[PCHUNK];
    const int c = blockIdx.x;        // clean image 0..7
    const int p = blockIdx.y;        // patch chunk 0..15
    const int bp = 8 + c;
    const int t = threadIdx.x;
    if (t < PCHUNK) {
        const int i = p * PCHUNK + t;
        const float4 v = boxes[bp * KMAX + i];
        pb[t] = v;
        par[t] = (v.z - v.x) * (v.w - v.y);
        pcls[t] = keep[bp * KMAX + i] ? cls[bp * KMAX + i] : -1;   // fold keep into class
    }
    __syncthreads();
    const float4 bc = boxes[c * KMAX + t];
    const int cc = cls[c * KMAX + t];
    const float area_c = (bc.z - bc.x) * (bc.w - bc.y);
    float tm = 0.f;
    #pragma unroll 8
    for (int i = 0; i < PCHUNK; ++i) {
        const float4 bi = pb[i];
        const float ax = fmaxf(bi.x, bc.x), ay = fmaxf(bi.y, bc.y);
        const float bx2 = fminf(bi.z, bc.z), by2 = fminf(bi.w, bc.w);
        const float iw = fmaxf(bx2 - ax, 0.f), ih = fmaxf(by2 - ay, 0.f);
        const float inter = iw * ih;
        const float iou = inter / (par[i] + area_c - inter);
        tm = fmaxf(tm, (pcls[i] == cc) ? iou : 0.f);
    }
    pmax[(c * 16 + p) * 256 + t] = tm;
}

// K8b: reduce over chunks, mask by clean keep, sum
__global__ __launch_bounds__(256) void k_match_reduce(const float* __restrict__ pmax,
                                                      const int* __restrict__ keep,
                                                      float* __restrict__ sums,
                                                      float* __restrict__ cnts)
{
    __shared__ float red[8];
    const int c = blockIdx.x;
    const int t = threadIdx.x;
    float tm = 0.f;
    #pragma unroll
    for (int p = 0; p < 16; ++p)
        tm = fmaxf(tm, pmax[(c * 16 + p) * 256 + t]);
    const int kc = keep[c * KMAX + t];
    float val = kc ? tm : 0.f;
    float cv  = kc ? 1.f : 0.f;
    for (int off = 32; off > 0; off >>= 1) {
        val += __shfl_down(val, off);
        cv  += __shfl_down(cv, off);
    }
    const int wv = t >> 6, lane = t & 63;
    if (lane == 0) { red[wv] = val; red[4 + wv] = cv; }
    __syncthreads();
    if (t == 0) {
        sums[c] = red[0] + red[1] + red[2] + red[3];
        cnts[c] = red[4] + red[5] + red[6] + red[7];
    }
}

// K9: scalar epilogue
__global__ void k_final(const float* __restrict__ sums,
                        const float* __restrict__ cnts,
                        float* __restrict__ out)
{
    if (threadIdx.x == 0 && blockIdx.x == 0) {
        float total = 0.f, cnt = 0.f;
        for (int c = 0; c < 8; ++c) { total += sums[c]; cnt += cnts[c]; }
        out[0] = (cnt > 0.f) ? (1.0f - total / fmaxf(cnt, 1.0f)) : 1.0f;
    }
}

extern "C" void kernel_launch(void* const* d_in, const int* in_sizes, int n_in,
                              void* d_out, int out_size, void* d_ws, size_t ws_size,
                              hipStream_t stream)
{
    if (ws_size < WS_NEED) return;
    const float* clean = (const float*)d_in[0];
    const float* patch = (const float*)d_in[1];
    float* out = (float*)d_out;
    char* ws = (char*)d_ws;

    u64*    keys = (u64*)(ws + OFF_KEYS);
    u64*    mask = (u64*)(ws + OFF_KEYS);   // reuses keys region after k_sort
    int*    hist = (int*)(ws + OFF_HIST);
    u64*    diag = (u64*)(ws + OFF_HIST);   // reuses hist region after k_thresh
    int*    tbin = (int*)(ws + OFF_TBIN);
    int*    ccnt = (int*)(ws + OFF_CCNT);
    float*  sums = (float*)(ws + OFF_SUMS);
    float*  cnts = (float*)(ws + OFF_CNTS);
    u64*    cand = (u64*)(ws + OFF_CAND);
    float*  pmax = (float*)(ws + OFF_CAND); // reuses cand region after k_sort
    u64*    sel  = (u64*)(ws + OFF_SEL);
    float4* boxes = (float4*)(ws + OFF_BOX);
    int*    cls  = (int*)(ws + OFF_CLS);
    u64*    rinit = (u64*)(ws + OFF_RINIT);
    int*    keep = (int*)(ws + OFF_KEEP);

    hipMemsetAsync(ws + OFF_HIST, 0, ZERO_BYTES, stream);

    k_score<<<(NIMG * SCHUNKS) / 2, 128, 0, stream>>>(clean, patch, keys);
    k_hist<<<dim3(NIMG, 16), 256, 0, stream>>>(keys, hist);
    k_thresh<<<NIMG, 1024, 0, stream>>>(hist, tbin);
    k_compact<<<dim3(NIMG, 16), 256, 0, stream>>>(keys, tbin, ccnt, cand);
    k_sort<<<NIMG, 1024, 0, stream>>>(cand, ccnt, sel);
    k_gather<<<NIMG, 1024, 0, stream>>>(clean, patch, sel, boxes, cls, rinit);
    k_nms_mask<<<dim3(NIMG, 16), 1024, 0, stream>>>(boxes, cls, mask, diag);
    k_nms_scan<<<NIMG, 1024, KMAX * 16 * 8 + KMAX * 8, stream>>>(mask, diag, rinit, keep);
    k_match_partial<<<dim3(8, 16), 256, 0, stream>>>(boxes, cls, keep, pmax);
    k_match_reduce<<<8, 256, 0, stream>>>(pmax, keep, sums, cnts);
    k_final<<<1, 64, 0, stream>>>(sums, cnts, out);
}

// Round 8
// 137.196 us; speedup vs baseline: 4.1865x; 1.2495x over previous
//
#include <hip/hip_runtime.h>

#define N_ANCH 25200
#define NCLS   80
#define ROW    85
#define NIMG   16
#define KMAX   1024
#define NBINS  4096
#define CAND_CAP 4096
#define SC_ROWS 64           // rows per block in k_score
#define SC_CHUNKS 394        // ceil(25200/64); last chunk has 48 valid rows
#define SC_FLOATS (SC_ROWS*ROW)   // 5440 floats = 21,760 B
#define PCHUNK 64            // patch boxes per match block
#define CCNT_STRIDE 16       // ints; one 64B line per image counter

typedef unsigned long long u64;
typedef unsigned int u32;

// ---------------- ws layout (bytes) ----------------
#define OFF_KEYS 0ull                      // 16*25200*8 = 3,225,600 ; reused as NMS mask (2 MB) after k_sort
#define OFF_HIST 3225600ull                // 16*4096*4  =   262,144 ; reused as diag (128 KB) after k_thresh
#define OFF_TBIN 3487744ull                // 16*4 = 64
#define OFF_CCNT 3487808ull                // 16*64 = 1,024 (padded: 1 line/counter)
#define OFF_SUMS 3488832ull                // 8*4 = 32
#define OFF_CNTS 3488864ull                // 8*4 = 32
#define OFF_CAND 3488896ull                // 16*4096*8 = 524,288 ; reused as pmax (128 KB) after k_sort
#define OFF_SEL  4013184ull                // 16*1024*8 = 131,072
#define OFF_BOX  4144256ull                // 16*1024*16 = 262,144
#define OFF_CLS  4406400ull                // 16*1024*4 = 65,536
#define OFF_RINIT 4471936ull               // 16*16*8 = 2,048 (initial removal bitmask)
#define OFF_KEEP 4473984ull                // 16*1024*4 = 65,536
#define WS_NEED  4539520ull
#define ZERO_BYTES (262144ull + 64 + 1024 + 32 + 32)   // hist..cnts contiguous

#define DMA16(gsrc, ldst) \
    __builtin_amdgcn_global_load_lds( \
        (const __attribute__((address_space(1))) void*)(gsrc), \
        (__attribute__((address_space(3))) void*)(ldst), 16, 0, 0)

__device__ __forceinline__ int key_bin(u64 key) {
    u32 hi = (u32)(key >> 32);
    if (hi == 0u) return 0;
    float conf = __uint_as_float(hi - 0x40000000u);
    int b = 1 + (int)(conf * 4093.0f);
    return b > 4094 ? 4094 : b;
}

__device__ __forceinline__ u64 readlane64(u64 v, int src) {
    u32 lo = (u32)__builtin_amdgcn_readlane((int)(u32)(v & 0xffffffffull), src);
    u32 hi = (u32)__builtin_amdgcn_readlane((int)(u32)(v >> 32), src);
    return ((u64)hi << 32) | (u64)lo;
}

__device__ __forceinline__ u64 shfl64_xor(u64 v, int m) {
    int lo = __shfl_xor((int)(u32)(v & 0xffffffffull), m, 64);
    int hi = __shfl_xor((int)(u32)(v >> 32), m, 64);
    return ((u64)(u32)hi << 32) | (u64)(u32)lo;
}

// K1: per-entry conf/cls/validity -> 64-bit sort key.
// Block = 64 rows, 128 threads. Staging: 22 x 1KB global_load_lds DMAs split
// across 2 waves (21.25 KB exact). Compute: 2 threads/row (40 classes each),
// merge via shfl_xor(1) keeping reference first-max tie-break.
// LDS 21.75 KB -> 7 blocks/CU = 14 waves/CU; all 128 lanes compute.
__global__ __launch_bounds__(128) void k_score(const float* __restrict__ clean,
                                               const float* __restrict__ patch,
                                               u64* __restrict__ keys)
{
    __shared__ float lbuf[SC_FLOATS];
    const int t = threadIdx.x;
    const int wv = t >> 6, lane = t & 63;
    const int bid = blockIdx.x;
    const int b = bid / SC_CHUNKS;
    const int chunk = bid - b * SC_CHUNKS;
    const float* bufbase = (b < 8) ? clean : patch;
    const float* ibase = bufbase + (size_t)((b < 8) ? b : b - 8) * N_ANCH * ROW;
    const int base = chunk * SC_ROWS;
    const float* g = ibase + (size_t)base * ROW;
    if (chunk != SC_CHUNKS - 1) {
        if (wv == 0) {
            #pragma unroll
            for (int u = 0; u < 11; ++u)
                DMA16(g + u * 256 + lane * 4, lbuf + u * 256);
        } else {
            #pragma unroll
            for (int u = 11; u < 21; ++u)
                DMA16(g + u * 256 + lane * 4, lbuf + u * 256);
            if (lane < 16)
                DMA16(g + 21 * 256 + lane * 4, lbuf + 21 * 256);
        }
    } else {
        // last chunk: clamp per-lane src to the input buffer's final float4
        const float* lim = bufbase + (size_t)8 * N_ANCH * ROW - 4;
        if (wv == 0) {
            #pragma unroll
            for (int u = 0; u < 11; ++u) {
                const float* s = g + u * 256 + lane * 4;
                if (s > lim) s = lim;
                DMA16(s, lbuf + u * 256);
            }
        } else {
            #pragma unroll
            for (int u = 11; u < 21; ++u) {
                const float* s = g + u * 256 + lane * 4;
                if (s > lim) s = lim;
                DMA16(s, lbuf + u * 256);
            }
            if (lane < 16) {
                const float* s = g + 21 * 256 + lane * 4;
                if (s > lim) s = lim;
                DMA16(s, lbuf + 21 * 256);
            }
        }
    }
    asm volatile("s_waitcnt vmcnt(0)" ::: "memory");
    __syncthreads();
    const int r = t >> 1, h = t & 1;
    const float* p = lbuf + r * ROW;
    const float obj = p[4];
    const int d0 = h * 40;
    float best = -1.0f; int bc = 0;
    #pragma unroll 8
    for (int d = 0; d < 40; ++d) {
        const float s = p[5 + d0 + d] * obj;
        if (s > best) { best = s; bc = d0 + d; }
    }
    const float obest = __shfl_xor(best, 1, 64);
    const int   obc   = __shfl_xor(bc, 1, 64);
    if (h == 0) {
        float fb = best; int fc = bc;
        if (obest > fb) { fb = obest; fc = obc; }   // strict: first-max tie-break
        const int row = base + r;
        if (row < N_ANCH) {
            const float th = (b < 8) ? 0.25f : 0.001f;
            const bool valid = (obj > th) && (fb > th);
            const u32 hi = valid ? (__float_as_uint(fb) + 0x40000000u) : 0u;
            const u32 nbar = 32767u - (u32)row;
            keys[(size_t)b * N_ANCH + row] =
                ((u64)hi << 32) | ((u64)nbar << 8) | (u64)(u32)fc;
        }
    }
}

// K2: per-image histogram of conf bins
__global__ __launch_bounds__(256) void k_hist(const u64* __restrict__ keys,
                                              int* __restrict__ hist)
{
    __shared__ int h[NBINS];
    const int b = blockIdx.x;
    for (int i = threadIdx.x; i < NBINS; i += 256) h[i] = 0;
    __syncthreads();
    const int start = blockIdx.y * 1575;
    const u64* kp = keys + (size_t)b * N_ANCH;
    for (int i = start + threadIdx.x; i < start + 1575; i += 256)
        atomicAdd(&h[key_bin(kp[i])], 1);
    __syncthreads();
    for (int i = threadIdx.x; i < NBINS; i += 256)
        if (h[i]) atomicAdd(&hist[b * NBINS + i], h[i]);
}

// K3: per-image suffix-scan over bins -> threshold bin
__global__ __launch_bounds__(1024) void k_thresh(const int* __restrict__ hist,
                                                 int* __restrict__ tbin)
{
    __shared__ int arr[1024];
    const int b = blockIdx.x;
    const int t = threadIdx.x;
    int hh[4];
    hh[0] = hist[b * NBINS + 4 * t + 0];
    hh[1] = hist[b * NBINS + 4 * t + 1];
    hh[2] = hist[b * NBINS + 4 * t + 2];
    hh[3] = hist[b * NBINS + 4 * t + 3];
    const int r = hh[0] + hh[1] + hh[2] + hh[3];
    arr[t] = r;
    __syncthreads();
    for (int off = 1; off < 1024; off <<= 1) {
        int v = (t + off < 1024) ? arr[t + off] : 0;
        __syncthreads();
        arr[t] += v;
        __syncthreads();
    }
    const int K = (b < 8) ? 256 : 1024;
    int cb = arr[t] - r;
    for (int d = 3; d >= 0; --d) {
        int ca = cb + hh[d];
        if (cb < K && ca >= K) tbin[b] = 4 * t + d;
        cb = ca;
    }
}

// K4: compact candidates with bin >= T (wave-aggregated atomics)
__global__ __launch_bounds__(256) void k_compact(const u64* __restrict__ keys,
                                                 const int* __restrict__ tbin,
                                                 int* __restrict__ ccnt,
                                                 u64* __restrict__ cand)
{
    const int b = blockIdx.x;
    const int T = tbin[b];
    const u64* kp = keys + (size_t)b * N_ANCH;
    const int start = blockIdx.y * 1575;
    const int lane = threadIdx.x & 63;
    #pragma unroll
    for (int it = 0; it < 7; ++it) {
        const int off = it * 256 + threadIdx.x;          // 0..1791
        const bool in = off < 1575;
        const u64 key = in ? kp[start + off] : 0ull;
        const bool cnd = in && (key_bin(key) >= T);
        const u64 bal = __ballot(cnd);
        if (bal) {
            int base = 0;
            if (lane == 0) base = atomicAdd(&ccnt[b * CCNT_STRIDE], __popcll(bal));
            base = __shfl(base, 0, 64);
            if (cnd) {
                const int pos = base + __popcll(bal & ((1ull << lane) - 1ull));
                if (pos < CAND_CAP) cand[(size_t)b * CAND_CAP + pos] = key;
            }
        }
    }
}

// K5: per-image bitonic sort (descending) of candidates, emit top-K keys
__global__ __launch_bounds__(1024) void k_sort(const u64* __restrict__ cand,
                                               const int* __restrict__ ccnt,
                                               u64* __restrict__ sel)
{
    __shared__ u64 sk[CAND_CAP];   // 32 KB
    const int b = blockIdx.x;
    const int C = min(ccnt[b * CCNT_STRIDE], CAND_CAP);
    const int t = threadIdx.x;
    #pragma unroll
    for (int p = 0; p < CAND_CAP / 1024; ++p) {
        int i = p * 1024 + t;
        sk[i] = (i < C) ? cand[(size_t)b * CAND_CAP + i] : 0ull;
    }
    __syncthreads();
    for (int k = 2; k <= CAND_CAP; k <<= 1) {
        for (int j = k >> 1; j > 0; j >>= 1) {
            #pragma unroll
            for (int p = 0; p < CAND_CAP / 1024; ++p) {
                int i = p * 1024 + t;
                int ixj = i ^ j;
                if (ixj > i) {
                    u64 a = sk[i], c = sk[ixj];
                    bool descSeg = ((i & k) == 0);
                    bool sw = descSeg ? (a < c) : (a > c);
                    if (sw) { sk[i] = c; sk[ixj] = a; }
                }
            }
            __syncthreads();
        }
    }
    const int K = (b < 8) ? 256 : 1024;
    if (t < K) sel[b * KMAX + t] = sk[t];
}

// K6: decode keys, gather boxes (xywh->xyxy), cls; ballot initial removal mask
__global__ __launch_bounds__(1024) void k_gather(const float* __restrict__ clean,
                                                 const float* __restrict__ patch,
                                                 const u64* __restrict__ sel,
                                                 float4* __restrict__ boxes,
                                                 int* __restrict__ cls,
                                                 u64* __restrict__ rinit)
{
    const int b = blockIdx.x;
    const int t = threadIdx.x;
    const int K = (b < 8) ? 256 : 1024;
    const u64 key = (t < K) ? sel[b * KMAX + t] : 0ull;
    const u32 hi = (u32)(key >> 32);
    const bool valid = (t < K) && (hi != 0u);
    u64 bal = __ballot(valid);
    if ((t & 63) == 0) rinit[b * 16 + (t >> 6)] = ~bal;
    if (t >= K) return;
    const int n = 32767 - (int)((key >> 8) & 0x7FFFu);
    const int c = (int)(key & 0x7Fu);
    const float* src = ((b < 8) ? (clean + (size_t)b * N_ANCH * ROW)
                                : (patch + (size_t)(b - 8) * N_ANCH * ROW)) + (size_t)n * ROW;
    const float x = src[0], y = src[1], w = src[2], h = src[3];
    boxes[b * KMAX + t] = make_float4(x - w * 0.5f, y - h * 0.5f, x + w * 0.5f, y + h * 0.5f);
    cls[b * KMAX + t] = c;
}

// K7a: parallel suppression-mask build. Wave = one 64-bit word column across 64 rows.
// Also emits the per-row DIAGONAL word (intra-group suppression) contiguously.
__global__ __launch_bounds__(1024) void k_nms_mask(const float4* __restrict__ boxes,
                                                   const int* __restrict__ cls,
                                                   u64* __restrict__ mask,
                                                   u64* __restrict__ diag)
{
    __shared__ float4 bx[KMAX];
    __shared__ float ar[KMAX];
    const int b = blockIdx.x;
    const int K = (b < 8) ? 256 : 1024;
    const int row0 = blockIdx.y * 64;
    if (row0 >= K) return;                  // block-uniform
    const int t = threadIdx.x;
    for (int i = t; i < K; i += 1024) {
        float4 v = boxes[b * KMAX + i];
        float off = (float)cls[b * KMAX + i] * 4096.0f;
        v.x += off; v.y += off; v.z += off; v.w += off;
        bx[i] = v;
        ar[i] = (v.z - v.x) * (v.w - v.y);
    }
    __syncthreads();
    const int w   = t >> 6;                 // word column (wave-uniform)
    const int row = row0 + (t & 63);        // lane-distinct row
    u64* dst = mask + ((size_t)b * KMAX + row) * 16 + w;
    if (((w << 6) + 63) <= row0 && row0 > 0) { *dst = 0ull; return; }   // all j <= min row: zero word
    const float4 bi = bx[row];
    const float ai = ar[row];
    const int jbase = w << 6;
    u64 m = 0;
    #pragma unroll 8
    for (int k = 0; k < 64; ++k) {
        const int j = jbase + k;            // wave-uniform -> LDS broadcast
        const float4 bj = bx[j];
        const float ax = fmaxf(bi.x, bj.x), ay = fmaxf(bi.y, bj.y);
        const float bx2 = fminf(bi.z, bj.z), by2 = fminf(bi.w, bj.w);
        const float iw = fmaxf(bx2 - ax, 0.f), ih = fmaxf(by2 - ay, 0.f);
        const float inter = iw * ih;
        const float iou = inter / (ai + ar[j] - inter);
        if (j > row && iou > 0.45f) m |= (1ull << k);
    }
    *dst = m;
    if (w == (row0 >> 6)) diag[(size_t)b * KMAX + row] = m;
}

// K7b: greedy scan, one block per image, mask+diag in LDS. Per 64-row group:
// Phase A: sparse serial chain — only rows with nonzero diag words can change
//   the chain (ballot + ctz loop, ~10-25 iters instead of 64).
// Phase B: 4 lanes per removal word (q=lane>>4), 16 reads each with dual
//   accumulators, OR-combined across q via 2 shfl_xor steps.
__global__ __launch_bounds__(1024) void k_nms_scan(const u64* __restrict__ mask,
                                                   const u64* __restrict__ diag,
                                                   const u64* __restrict__ rinit,
                                                   int* __restrict__ keep)
{
    extern __shared__ u64 smem[];           // K*16 mask + K diag
    const int b = blockIdx.x;
    const int K = (b < 8) ? 256 : 1024;
    const int W = K >> 6;
    const int t = threadIdx.x;
    u64* smask = smem;
    u64* sdiag = smem + (size_t)K * 16;
    {
        const float4* s4 = (const float4*)(mask + (size_t)b * KMAX * 16);
        float4* d4 = (float4*)smask;
        const int n4 = (K * 16) >> 1;
        for (int i = t; i < n4; i += 1024) d4[i] = s4[i];
        const float4* s4d = (const float4*)(diag + (size_t)b * KMAX);
        float4* d4d = (float4*)sdiag;
        for (int i = t; i < (K >> 1); i += 1024) d4d[i] = s4d[i];
    }
    __syncthreads();
    if (t >= 64) return;
    const int lane = t;
    const int q = lane >> 4;                // 0..3: row sub-block within group
    const int wl = lane & 15;               // removal word owned by this lane
    u64 w_remv = rinit[b * 16 + wl];
    u64 ow = readlane64(w_remv, 0);
    u64 dj = sdiag[lane];
    for (int g = 0; g < W; ++g) {
        // Phase A: sparse keep chain (wave-uniform scalar loop)
        u64 nz = __ballot(dj != 0ull);
        u64 o = ow;
        while (nz) {
            const int j = (int)__builtin_ctzll(nz);
            nz &= nz - 1;
            if (!((o >> j) & 1ull)) o |= readlane64(dj, j);
        }
        const u64 kept = ~o;
        if (g + 1 < W) dj = sdiag[(g + 1) * 64 + lane];   // prefetch next diag
        // Phase B: this lane ORs rows [q*16, q*16+16) of word wl
        const u64* mrow = smask + (size_t)(g * 64 + q * 16) * 16 + wl;
        const u32 kg = (u32)((kept >> (q * 16)) & 0xFFFFull);
        u64 a0 = 0, a1 = 0;
        #pragma unroll
        for (int i = 0; i < 16; i += 2) {
            const u64 m0 = mrow[(size_t)(i + 0) * 16];
            const u64 m1 = mrow[(size_t)(i + 1) * 16];
            a0 |= ((kg >> i) & 1u) ? m0 : 0ull;
            a1 |= ((kg >> (i + 1)) & 1u) ? m1 : 0ull;
        }
        u64 part = a0 | a1;
        part |= shfl64_xor(part, 16);
        part |= shfl64_xor(part, 32);
        w_remv |= part;
        if (g + 1 < W) ow = readlane64(w_remv, g + 1);
    }
    if (lane < W) {
        #pragma unroll
        for (int k = 0; k < 64; ++k)
            keep[b * KMAX + lane * 64 + k] = (int)(((w_remv >> k) & 1) ^ 1ull);
    }
}

// K8a: partial max IoU: block = (clean image, patch chunk of 64). Branchless inner loop.
__global__ __launch_bounds__(256) void k_match_partial(const float4* __restrict__ boxes,
                                                       const int* __restrict__ cls,
                                                       const int* __restrict__ keep,
                                                       float* __restrict__ pmax)
{
    __shared__ float4 pb[PCHUNK];
    __shared__ float par[PCHUNK];
    __shared__ int pcls[PCHUNK];
    const int c = blockIdx.x;        // clean image 0..7
    const int p = blockIdx.y;        // patch chunk 0..15
    const int bp = 8 + c;
    const int t = threadIdx.x;
    if (t < PCHUNK) {
        const int i = p * PCHUNK + t;
        const float4 v = boxes[bp * KMAX + i];
        pb[t] = v;
        par[t] = (v.z - v.x) * (v.w - v.y);
        pcls[t] = keep[bp * KMAX + i] ? cls[bp * KMAX + i] : -1;   // fold keep into class
    }
    __syncthreads();
    const float4 bc = boxes[c * KMAX + t];
    const int cc = cls[c * KMAX + t];
    const float area_c = (bc.z - bc.x) * (bc.w - bc.y);
    float tm = 0.f;
    #pragma unroll 8
    for (int i = 0; i < PCHUNK; ++i) {
        const float4 bi = pb[i];
        const float ax = fmaxf(bi.x, bc.x), ay = fmaxf(bi.y, bc.y);
        const float bx2 = fminf(bi.z, bc.z), by2 = fminf(bi.w, bc.w);
        const float iw = fmaxf(bx2 - ax, 0.f), ih = fmaxf(by2 - ay, 0.f);
        const float inter = iw * ih;
        const float iou = inter / (par[i] + area_c - inter);
        tm = fmaxf(tm, (pcls[i] == cc) ? iou : 0.f);
    }
    pmax[(c * 16 + p) * 256 + t] = tm;
}

// K8b: reduce over chunks, mask by clean keep, sum
__global__ __launch_bounds__(256) void k_match_reduce(const float* __restrict__ pmax,
                                                      const int* __restrict__ keep,
                                                      float* __restrict__ sums,
                                                      float* __restrict__ cnts)
{
    __shared__ float red[8];
    const int c = blockIdx.x;
    const int t = threadIdx.x;
    float tm = 0.f;
    #pragma unroll
    for (int p = 0; p < 16; ++p)
        tm = fmaxf(tm, pmax[(c * 16 + p) * 256 + t]);
    const int kc = keep[c * KMAX + t];
    float val = kc ? tm : 0.f;
    float cv  = kc ? 1.f : 0.f;
    for (int off = 32; off > 0; off >>= 1) {
        val += __shfl_down(val, off);
        cv  += __shfl_down(cv, off);
    }
    const int wv = t >> 6, lane = t & 63;
    if (lane == 0) { red[wv] = val; red[4 + wv] = cv; }
    __syncthreads();
    if (t == 0) {
        sums[c] = red[0] + red[1] + red[2] + red[3];
        cnts[c] = red[4] + red[5] + red[6] + red[7];
    }
}

// K9: scalar epilogue
__global__ void k_final(const float* __restrict__ sums,
                        const float* __restrict__ cnts,
                        float* __restrict__ out)
{
    if (threadIdx.x == 0 && blockIdx.x == 0) {
        float total = 0.f, cnt = 0.f;
        for (int c = 0; c < 8; ++c) { total += sums[c]; cnt += cnts[c]; }
        out[0] = (cnt > 0.f) ? (1.0f - total / fmaxf(cnt, 1.0f)) : 1.0f;
    }
}

extern "C" void kernel_launch(void* const* d_in, const int* in_sizes, int n_in,
                              void* d_out, int out_size, void* d_ws, size_t ws_size,
                              hipStream_t stream)
{
    if (ws_size < WS_NEED) return;
    const float* clean = (const float*)d_in[0];
    const float* patch = (const float*)d_in[1];
    float* out = (float*)d_out;
    char* ws = (char*)d_ws;

    u64*    keys = (u64*)(ws + OFF_KEYS);
    u64*    mask = (u64*)(ws + OFF_KEYS);   // reuses keys region after k_sort
    int*    hist = (int*)(ws + OFF_HIST);
    u64*    diag = (u64*)(ws + OFF_HIST);   // reuses hist region after k_thresh
    int*    tbin = (int*)(ws + OFF_TBIN);
    int*    ccnt = (int*)(ws + OFF_CCNT);
    float*  sums = (float*)(ws + OFF_SUMS);
    float*  cnts = (float*)(ws + OFF_CNTS);
    u64*    cand = (u64*)(ws + OFF_CAND);
    float*  pmax = (float*)(ws + OFF_CAND); // reuses cand region after k_sort
    u64*    sel  = (u64*)(ws + OFF_SEL);
    float4* boxes = (float4*)(ws + OFF_BOX);
    int*    cls  = (int*)(ws + OFF_CLS);
    u64*    rinit = (u64*)(ws + OFF_RINIT);
    int*    keep = (int*)(ws + OFF_KEEP);

    hipMemsetAsync(ws + OFF_HIST, 0, ZERO_BYTES, stream);

    k_score<<<NIMG * SC_CHUNKS, 128, 0, stream>>>(clean, patch, keys);
    k_hist<<<dim3(NIMG, 16), 256, 0, stream>>>(keys, hist);
    k_thresh<<<NIMG, 1024, 0, stream>>>(hist, tbin);
    k_compact<<<dim3(NIMG, 16), 256, 0, stream>>>(keys, tbin, ccnt, cand);
    k_sort<<<NIMG, 1024, 0, stream>>>(cand, ccnt, sel);
    k_gather<<<NIMG, 1024, 0, stream>>>(clean, patch, sel, boxes, cls, rinit);
    k_nms_mask<<<dim3(NIMG, 16), 1024, 0, stream>>>(boxes, cls, mask, diag);
    k_nms_scan<<<NIMG, 1024, KMAX * 16 * 8 + KMAX * 8, stream>>>(mask, diag, rinit, keep);
    k_match_partial<<<dim3(8, 16), 256, 0, stream>>>(boxes, cls, keep, pmax);
    k_match_reduce<<<8, 256, 0, stream>>>(pmax, keep, sums, cnts);
    k_final<<<1, 64, 0, stream>>>(sums, cnts, out);
}

// Round 9
// 136.137 us; speedup vs baseline: 4.2190x; 1.0078x over previous
//
#include <hip/hip_runtime.h>

#define N_ANCH 25200
#define NCLS   80
#define ROW    85
#define NIMG   16
#define KMAX   1024
#define NBINS  4096
#define CAND_CAP 4096
#define SC2_RPC 16                 // rows per chunk (25200 = 1575*16)
#define SC2_CPI 1575               // chunks per image
#define SC2_CHUNKS (NIMG * SC2_CPI)
#define SC2_CFLOATS (SC2_RPC * ROW)   // 1360 floats = 5440 B
#define SC2_BLOCKS 1792            // 7 blocks/CU * 256 CU
#define PCHUNK 64                  // patch boxes per match block
#define CCNT_STRIDE 16             // ints; one 64B line per image counter

typedef unsigned long long u64;
typedef unsigned int u32;

// ---------------- ws layout (bytes) ----------------
#define OFF_KEYS 0ull                      // 16*25200*8 = 3,225,600 ; reused as NMS mask (2 MB) after k_sort
#define OFF_HIST 3225600ull                // 16*4096*4  =   262,144 ; reused as diag (128 KB) after k_thresh
#define OFF_TBIN 3487744ull                // 16*4 = 64
#define OFF_CCNT 3487808ull                // 16*64 = 1,024 (padded: 1 line/counter)
#define OFF_SUMS 3488832ull                // 8*4 = 32
#define OFF_CNTS 3488864ull                // 8*4 = 32
#define OFF_CAND 3488896ull                // 16*4096*8 = 524,288 ; reused as pmax (128 KB) after k_sort
#define OFF_SEL  4013184ull                // 16*1024*8 = 131,072
#define OFF_BOX  4144256ull                // 16*1024*16 = 262,144
#define OFF_CLS  4406400ull                // 16*1024*4 = 65,536
#define OFF_RINIT 4471936ull               // 16*16*8 = 2,048 (initial removal bitmask)
#define OFF_KEEP 4473984ull                // 16*1024*4 = 65,536
#define WS_NEED  4539520ull
#define ZERO_BYTES (262144ull + 64 + 1024 + 32 + 32)   // hist..cnts contiguous

#define DMA16(gsrc, ldst) \
    __builtin_amdgcn_global_load_lds( \
        (const __attribute__((address_space(1))) void*)(gsrc), \
        (__attribute__((address_space(3))) void*)(ldst), 16, 0, 0)

__device__ __forceinline__ int key_bin(u64 key) {
    u32 hi = (u32)(key >> 32);
    if (hi == 0u) return 0;
    float conf = __uint_as_float(hi - 0x40000000u);
    int b = 1 + (int)(conf * 4093.0f);
    return b > 4094 ? 4094 : b;
}

__device__ __forceinline__ u64 readlane64(u64 v, int src) {
    u32 lo = (u32)__builtin_amdgcn_readlane((int)(u32)(v & 0xffffffffull), src);
    u32 hi = (u32)__builtin_amdgcn_readlane((int)(u32)(v >> 32), src);
    return ((u64)hi << 32) | (u64)lo;
}

__device__ __forceinline__ u64 shfl64_xor(u64 v, int m) {
    int lo = __shfl_xor((int)(u32)(v & 0xffffffffull), m, 64);
    int hi = __shfl_xor((int)(u32)(v >> 32), m, 64);
    return ((u64)(u32)hi << 32) | (u64)(u32)lo;
}

// ---- k_score helpers: persistent-wave double-buffered pipeline ----
__device__ __forceinline__ void sc_issue(const float* __restrict__ clean,
                                         const float* __restrict__ patch,
                                         int c, int lane, float* buf)
{
    const int b = c / SC2_CPI;
    const int ch = c - b * SC2_CPI;
    const float* g = ((b < 8) ? clean + (size_t)b * N_ANCH * ROW
                              : patch + (size_t)(b - 8) * N_ANCH * ROW)
                     + (size_t)ch * SC2_CFLOATS;
    #pragma unroll
    for (int u = 0; u < 5; ++u)
        DMA16(g + u * 256 + lane * 4, buf + u * 256);
    if (lane < 20)
        DMA16(g + 5 * 256 + lane * 4, buf + 5 * 256);     // floats 1280..1359
}

__device__ __forceinline__ void sc_compute(int c, int lane,
                                           const float* buf, u64* __restrict__ keys)
{
    const int b = c / SC2_CPI;
    const int ch = c - b * SC2_CPI;
    const int r = lane & 15, h = lane >> 4;      // 4 lanes per row, 20 classes each
    const float* p = buf + r * ROW;
    const float obj = p[4];
    float best = -1.0f; int bc = 0;
    #pragma unroll
    for (int d = 0; d < 20; ++d) {
        const float s = p[5 + h * 20 + d] * obj;
        if (s > best) { best = s; bc = h * 20 + d; }
    }
    // merge across h groups; on equal value prefer smaller class idx (first-max)
    #pragma unroll
    for (int m = 16; m <= 32; m <<= 1) {
        const float o = __shfl_xor(best, m, 64);
        const int  oc = __shfl_xor(bc, m, 64);
        if (o > best || (o == best && oc < bc)) { best = o; bc = oc; }
    }
    if (h == 0) {
        const int n = ch * SC2_RPC + r;
        const float th = (b < 8) ? 0.25f : 0.001f;
        const bool valid = (obj > th) && (best > th);
        const u32 hi = valid ? (__float_as_uint(best) + 0x40000000u) : 0u;
        const u32 nbar = 32767u - (u32)n;
        keys[(size_t)b * N_ANCH + n] =
            ((u64)hi << 32) | ((u64)nbar << 8) | (u64)(u32)bc;
    }
}

// K1: persistent waves, grid-stride over 16-row chunks, double-buffered
// global_load_lds with counted vmcnt(6) — every wave keeps one chunk of
// loads in flight at all times. No barriers (buffers are wave-private).
__global__ __launch_bounds__(128) void k_score(const float* __restrict__ clean,
                                               const float* __restrict__ patch,
                                               u64* __restrict__ keys)
{
    __shared__ float lds[2][2][SC2_CFLOATS];     // 21,760 B -> 7 blocks/CU (14 waves)
    const int wv = threadIdx.x >> 6, lane = threadIdx.x & 63;
    const int wid = blockIdx.x * 2 + wv;
    const int stride = SC2_BLOCKS * 2;
    int cur = 0;
    sc_issue(clean, patch, wid, lane, &lds[wv][0][0]);
    for (int c = wid; c < SC2_CHUNKS; c += stride) {
        const int cn = c + stride;
        if (cn < SC2_CHUNKS) {
            sc_issue(clean, patch, cn, lane, &lds[wv][cur ^ 1][0]);
            asm volatile("s_waitcnt vmcnt(6)" ::: "memory");
        } else {
            asm volatile("s_waitcnt vmcnt(0)" ::: "memory");
        }
        __builtin_amdgcn_sched_barrier(0);
        sc_compute(c, lane, &lds[wv][cur][0], keys);
        cur ^= 1;
    }
}

// K2: per-image histogram of conf bins
__global__ __launch_bounds__(256) void k_hist(const u64* __restrict__ keys,
                                              int* __restrict__ hist)
{
    __shared__ int h[NBINS];
    const int b = blockIdx.x;
    for (int i = threadIdx.x; i < NBINS; i += 256) h[i] = 0;
    __syncthreads();
    const int start = blockIdx.y * 1575;
    const u64* kp = keys + (size_t)b * N_ANCH;
    for (int i = start + threadIdx.x; i < start + 1575; i += 256)
        atomicAdd(&h[key_bin(kp[i])], 1);
    __syncthreads();
    for (int i = threadIdx.x; i < NBINS; i += 256)
        if (h[i]) atomicAdd(&hist[b * NBINS + i], h[i]);
}

// K3: per-image suffix-scan over bins -> threshold bin
__global__ __launch_bounds__(1024) void k_thresh(const int* __restrict__ hist,
                                                 int* __restrict__ tbin)
{
    __shared__ int arr[1024];
    const int b = blockIdx.x;
    const int t = threadIdx.x;
    int hh[4];
    hh[0] = hist[b * NBINS + 4 * t + 0];
    hh[1] = hist[b * NBINS + 4 * t + 1];
    hh[2] = hist[b * NBINS + 4 * t + 2];
    hh[3] = hist[b * NBINS + 4 * t + 3];
    const int r = hh[0] + hh[1] + hh[2] + hh[3];
    arr[t] = r;
    __syncthreads();
    for (int off = 1; off < 1024; off <<= 1) {
        int v = (t + off < 1024) ? arr[t + off] : 0;
        __syncthreads();
        arr[t] += v;
        __syncthreads();
    }
    const int K = (b < 8) ? 256 : 1024;
    int cb = arr[t] - r;
    for (int d = 3; d >= 0; --d) {
        int ca = cb + hh[d];
        if (cb < K && ca >= K) tbin[b] = 4 * t + d;
        cb = ca;
    }
}

// K4: compact candidates with bin >= T (wave-aggregated atomics)
__global__ __launch_bounds__(256) void k_compact(const u64* __restrict__ keys,
                                                 const int* __restrict__ tbin,
                                                 int* __restrict__ ccnt,
                                                 u64* __restrict__ cand)
{
    const int b = blockIdx.x;
    const int T = tbin[b];
    const u64* kp = keys + (size_t)b * N_ANCH;
    const int start = blockIdx.y * 1575;
    const int lane = threadIdx.x & 63;
    #pragma unroll
    for (int it = 0; it < 7; ++it) {
        const int off = it * 256 + threadIdx.x;          // 0..1791
        const bool in = off < 1575;
        const u64 key = in ? kp[start + off] : 0ull;
        const bool cnd = in && (key_bin(key) >= T);
        const u64 bal = __ballot(cnd);
        if (bal) {
            int base = 0;
            if (lane == 0) base = atomicAdd(&ccnt[b * CCNT_STRIDE], __popcll(bal));
            base = __shfl(base, 0, 64);
            if (cnd) {
                const int pos = base + __popcll(bal & ((1ull << lane) - 1ull));
                if (pos < CAND_CAP) cand[(size_t)b * CAND_CAP + pos] = key;
            }
        }
    }
}

// K5: per-image bitonic sort (descending), hybrid register/shuffle/LDS.
// 4 elements/thread at index i = p*1024 + t:
//   j >= 1024 -> register swaps (no comms); 64 <= j <= 512 -> LDS (2 barriers);
//   j <= 32   -> shfl_xor (no barriers). 36 barriers total vs 78 before.
__global__ __launch_bounds__(1024) void k_sort(const u64* __restrict__ cand,
                                               const int* __restrict__ ccnt,
                                               u64* __restrict__ sel)
{
    __shared__ u64 sk[CAND_CAP];   // 32 KB
    const int b = blockIdx.x;
    const int C = min(ccnt[b * CCNT_STRIDE], CAND_CAP);
    const int t = threadIdx.x;
    u64 e0, e1, e2, e3;
    e0 = (t < C) ? cand[(size_t)b * CAND_CAP + t] : 0ull;
    e1 = (1024 + t < C) ? cand[(size_t)b * CAND_CAP + 1024 + t] : 0ull;
    e2 = (2048 + t < C) ? cand[(size_t)b * CAND_CAP + 2048 + t] : 0ull;
    e3 = (3072 + t < C) ? cand[(size_t)b * CAND_CAP + 3072 + t] : 0ull;

    #define CSWAP_D(a, c) { if ((a) < (c)) { u64 _t = (a); (a) = (c); (c) = _t; } }
    #define CSWAP_A(a, c) { if ((a) > (c)) { u64 _t = (a); (a) = (c); (c) = _t; } }

    for (int k = 2; k <= 4096; k <<= 1) {
        for (int j = k >> 1; j > 0; j >>= 1) {
            if (j >= 1024) {
                if (j == 2048) {            // k==4096: desc everywhere
                    CSWAP_D(e0, e2); CSWAP_D(e1, e3);
                } else {                    // j==1024
                    if (k == 4096) { CSWAP_D(e0, e1); CSWAP_D(e2, e3); }
                    else           { CSWAP_D(e0, e1); CSWAP_A(e2, e3); }  // k==2048
                }
            } else if (j >= 64) {
                __syncthreads();
                sk[t] = e0; sk[1024 + t] = e1; sk[2048 + t] = e2; sk[3072 + t] = e3;
                __syncthreads();
                const int tp = t ^ j;
                #pragma unroll
                for (int p = 0; p < 4; ++p) {
                    const int i = p * 1024 + t;
                    const u64 cv = (p == 0) ? e0 : (p == 1) ? e1 : (p == 2) ? e2 : e3;
                    const u64 o = sk[p * 1024 + tp];
                    const bool take_max = (((i & k) == 0) == ((t & j) == 0));
                    const u64 mx = cv > o ? cv : o;
                    const u64 mn = cv > o ? o : cv;
                    const u64 nv = take_max ? mx : mn;
                    if (p == 0) e0 = nv; else if (p == 1) e1 = nv;
                    else if (p == 2) e2 = nv; else e3 = nv;
                }
            } else {
                #pragma unroll
                for (int p = 0; p < 4; ++p) {
                    const int i = p * 1024 + t;
                    const u64 cv = (p == 0) ? e0 : (p == 1) ? e1 : (p == 2) ? e2 : e3;
                    const u64 o = shfl64_xor(cv, j);
                    const bool take_max = (((i & k) == 0) == ((t & j) == 0));
                    const u64 mx = cv > o ? cv : o;
                    const u64 mn = cv > o ? o : cv;
                    const u64 nv = take_max ? mx : mn;
                    if (p == 0) e0 = nv; else if (p == 1) e1 = nv;
                    else if (p == 2) e2 = nv; else e3 = nv;
                }
            }
        }
    }
    const int K = (b < 8) ? 256 : 1024;
    if (t < K) sel[b * KMAX + t] = e0;      // indices 0..K-1 live in p==0
    #undef CSWAP_D
    #undef CSWAP_A
}

// K6: decode keys, gather boxes (xywh->xyxy), cls; ballot initial removal mask
__global__ __launch_bounds__(1024) void k_gather(const float* __restrict__ clean,
                                                 const float* __restrict__ patch,
                                                 const u64* __restrict__ sel,
                                                 float4* __restrict__ boxes,
                                                 int* __restrict__ cls,
                                                 u64* __restrict__ rinit)
{
    const int b = blockIdx.x;
    const int t = threadIdx.x;
    const int K = (b < 8) ? 256 : 1024;
    const u64 key = (t < K) ? sel[b * KMAX + t] : 0ull;
    const u32 hi = (u32)(key >> 32);
    const bool valid = (t < K) && (hi != 0u);
    u64 bal = __ballot(valid);
    if ((t & 63) == 0) rinit[b * 16 + (t >> 6)] = ~bal;
    if (t >= K) return;
    const int n = 32767 - (int)((key >> 8) & 0x7FFFu);
    const int c = (int)(key & 0x7Fu);
    const float* src = ((b < 8) ? (clean + (size_t)b * N_ANCH * ROW)
                                : (patch + (size_t)(b - 8) * N_ANCH * ROW)) + (size_t)n * ROW;
    const float x = src[0], y = src[1], w = src[2], h = src[3];
    boxes[b * KMAX + t] = make_float4(x - w * 0.5f, y - h * 0.5f, x + w * 0.5f, y + h * 0.5f);
    cls[b * KMAX + t] = c;
}

// K7a: parallel suppression-mask build. Wave = one 64-bit word column across 64 rows.
// Also emits the per-row DIAGONAL word (intra-group suppression) contiguously.
__global__ __launch_bounds__(1024) void k_nms_mask(const float4* __restrict__ boxes,
                                                   const int* __restrict__ cls,
                                                   u64* __restrict__ mask,
                                                   u64* __restrict__ diag)
{
    __shared__ float4 bx[KMAX];
    __shared__ float ar[KMAX];
    const int b = blockIdx.x;
    const int K = (b < 8) ? 256 : 1024;
    const int row0 = blockIdx.y * 64;
    if (row0 >= K) return;                  // block-uniform
    const int t = threadIdx.x;
    for (int i = t; i < K; i += 1024) {
        float4 v = boxes[b * KMAX + i];
        float off = (float)cls[b * KMAX + i] * 4096.0f;
        v.x += off; v.y += off; v.z += off; v.w += off;
        bx[i] = v;
        ar[i] = (v.z - v.x) * (v.w - v.y);
    }
    __syncthreads();
    const int w   = t >> 6;                 // word column (wave-uniform)
    const int row = row0 + (t & 63);        // lane-distinct row
    u64* dst = mask + ((size_t)b * KMAX + row) * 16 + w;
    if (((w << 6) + 63) <= row0 && row0 > 0) { *dst = 0ull; return; }   // all j <= min row: zero word
    const float4 bi = bx[row];
    const float ai = ar[row];
    const int jbase = w << 6;
    u64 m = 0;
    #pragma unroll 8
    for (int k = 0; k < 64; ++k) {
        const int j = jbase + k;            // wave-uniform -> LDS broadcast
        const float4 bj = bx[j];
        const float ax = fmaxf(bi.x, bj.x), ay = fmaxf(bi.y, bj.y);
        const float bx2 = fminf(bi.z, bj.z), by2 = fminf(bi.w, bj.w);
        const float iw = fmaxf(bx2 - ax, 0.f), ih = fmaxf(by2 - ay, 0.f);
        const float inter = iw * ih;
        const float iou = inter / (ai + ar[j] - inter);
        if (j > row && iou > 0.45f) m |= (1ull << k);
    }
    *dst = m;
    if (w == (row0 >> 6)) diag[(size_t)b * KMAX + row] = m;
}

// K7b: greedy scan, one block per image, mask+diag in LDS. Per 64-row group:
// Phase A: sparse serial chain over nonzero diag rows (ballot + ctz);
// Phase B: 4 lanes per removal word, 16 reads each, OR-combined via shfl_xor.
__global__ __launch_bounds__(1024) void k_nms_scan(const u64* __restrict__ mask,
                                                   const u64* __restrict__ diag,
                                                   const u64* __restrict__ rinit,
                                                   int* __restrict__ keep)
{
    extern __shared__ u64 smem[];           // K*16 mask + K diag
    const int b = blockIdx.x;
    const int K = (b < 8) ? 256 : 1024;
    const int W = K >> 6;
    const int t = threadIdx.x;
    u64* smask = smem;
    u64* sdiag = smem + (size_t)K * 16;
    {
        const float4* s4 = (const float4*)(mask + (size_t)b * KMAX * 16);
        float4* d4 = (float4*)smask;
        const int n4 = (K * 16) >> 1;
        for (int i = t; i < n4; i += 1024) d4[i] = s4[i];
        const float4* s4d = (const float4*)(diag + (size_t)b * KMAX);
        float4* d4d = (float4*)sdiag;
        for (int i = t; i < (K >> 1); i += 1024) d4d[i] = s4d[i];
    }
    __syncthreads();
    if (t >= 64) return;
    const int lane = t;
    const int q = lane >> 4;                // 0..3: row sub-block within group
    const int wl = lane & 15;               // removal word owned by this lane
    u64 w_remv = rinit[b * 16 + wl];
    u64 ow = readlane64(w_remv, 0);
    u64 dj = sdiag[lane];
    for (int g = 0; g < W; ++g) {
        u64 nz = __ballot(dj != 0ull);
        u64 o = ow;
        while (nz) {
            const int j = (int)__builtin_ctzll(nz);
            nz &= nz - 1;
            if (!((o >> j) & 1ull)) o |= readlane64(dj, j);
        }
        const u64 kept = ~o;
        if (g + 1 < W) dj = sdiag[(g + 1) * 64 + lane];   // prefetch next diag
        const u64* mrow = smask + (size_t)(g * 64 + q * 16) * 16 + wl;
        const u32 kg = (u32)((kept >> (q * 16)) & 0xFFFFull);
        u64 a0 = 0, a1 = 0;
        #pragma unroll
        for (int i = 0; i < 16; i += 2) {
            const u64 m0 = mrow[(size_t)(i + 0) * 16];
            const u64 m1 = mrow[(size_t)(i + 1) * 16];
            a0 |= ((kg >> i) & 1u) ? m0 : 0ull;
            a1 |= ((kg >> (i + 1)) & 1u) ? m1 : 0ull;
        }
        u64 part = a0 | a1;
        part |= shfl64_xor(part, 16);
        part |= shfl64_xor(part, 32);
        w_remv |= part;
        if (g + 1 < W) ow = readlane64(w_remv, g + 1);
    }
    if (lane < W) {
        #pragma unroll
        for (int k = 0; k < 64; ++k)
            keep[b * KMAX + lane * 64 + k] = (int)(((w_remv >> k) & 1) ^ 1ull);
    }
}

// K8a: partial max IoU: block = (clean image, patch chunk of 64). Branchless inner loop.
__global__ __launch_bounds__(256) void k_match_partial(const float4* __restrict__ boxes,
                                                       const int* __restrict__ cls,
                                                       const int* __restrict__ keep,
                                                       float* __restrict__ pmax)
{
    __shared__ float4 pb[PCHUNK];
    __shared__ float par[PCHUNK];
    __shared__ int pcls[PCHUNK];
    const int c = blockIdx.x;        // clean image 0..7
    const int p = blockIdx.y;        // patch chunk 0..15
    const int bp = 8 + c;
    const int t = threadIdx.x;
    if (t < PCHUNK) {
        const int i = p * PCHUNK + t;
        const float4 v = boxes[bp * KMAX + i];
        pb[t] = v;
        par[t] = (v.z - v.x) * (v.w - v.y);
        pcls[t] = keep[bp * KMAX + i] ? cls[bp * KMAX + i] : -1;   // fold keep into class
    }
    __syncthreads();
    const float4 bc = boxes[c * KMAX + t];
    const int cc = cls[c * KMAX + t];
    const float area_c = (bc.z - bc.x) * (bc.w - bc.y);
    float tm = 0.f;
    #pragma unroll 8
    for (int i = 0; i < PCHUNK; ++i) {
        const float4 bi = pb[i];
        const float ax = fmaxf(bi.x, bc.x), ay = fmaxf(bi.y, bc.y);
        const float bx2 = fminf(bi.z, bc.z), by2 = fminf(bi.w, bc.w);
        const float iw = fmaxf(bx2 - ax, 0.f), ih = fmaxf(by2 - ay, 0.f);
        const float inter = iw * ih;
        const float iou = inter / (par[i] + area_c - inter);
        tm = fmaxf(tm, (pcls[i] == cc) ? iou : 0.f);
    }
    pmax[(c * 16 + p) * 256 + t] = tm;
}

// K8b: reduce over chunks, mask by clean keep, sum
__global__ __launch_bounds__(256) void k_match_reduce(const float* __restrict__ pmax,
                                                      const int* __restrict__ keep,
                                                      float* __restrict__ sums,
                                                      float* __restrict__ cnts)
{
    __shared__ float red[8];
    const int c = blockIdx.x;
    const int t = threadIdx.x;
    float tm = 0.f;
    #pragma unroll
    for (int p = 0; p < 16; ++p)
        tm = fmaxf(tm, pmax[(c * 16 + p) * 256 + t]);
    const int kc = keep[c * KMAX + t];
    float val = kc ? tm : 0.f;
    float cv  = kc ? 1.f : 0.f;
    for (int off = 32; off > 0; off >>= 1) {
        val += __shfl_down(val, off);
        cv  += __shfl_down(cv, off);
    }
    const int wv = t >> 6, lane = t & 63;
    if (lane == 0) { red[wv] = val; red[4 + wv] = cv; }
    __syncthreads();
    if (t == 0) {
        sums[c] = red[0] + red[1] + red[2] + red[3];
        cnts[c] = red[4] + red[5] + red[6] + red[7];
    }
}

// K9: scalar epilogue
__global__ void k_final(const float* __restrict__ sums,
                        const float* __restrict__ cnts,
                        float* __restrict__ out)
{
    if (threadIdx.x == 0 && blockIdx.x == 0) {
        float total = 0.f, cnt = 0.f;
        for (int c = 0; c < 8; ++c) { total += sums[c]; cnt += cnts[c]; }
        out[0] = (cnt > 0.f) ? (1.0f - total / fmaxf(cnt, 1.0f)) : 1.0f;
    }
}

extern "C" void kernel_launch(void* const* d_in, const int* in_sizes, int n_in,
                              void* d_out, int out_size, void* d_ws, size_t ws_size,
                              hipStream_t stream)
{
    if (ws_size < WS_NEED) return;
    const float* clean = (const float*)d_in[0];
    const float* patch = (const float*)d_in[1];
    float* out = (float*)d_out;
    char* ws = (char*)d_ws;

    u64*    keys = (u64*)(ws + OFF_KEYS);
    u64*    mask = (u64*)(ws + OFF_KEYS);   // reuses keys region after k_sort
    int*    hist = (int*)(ws + OFF_HIST);
    u64*    diag = (u64*)(ws + OFF_HIST);   // reuses hist region after k_thresh
    int*    tbin = (int*)(ws + OFF_TBIN);
    int*    ccnt = (int*)(ws + OFF_CCNT);
    float*  sums = (float*)(ws + OFF_SUMS);
    float*  cnts = (float*)(ws + OFF_CNTS);
    u64*    cand = (u64*)(ws + OFF_CAND);
    float*  pmax = (float*)(ws + OFF_CAND); // reuses cand region after k_sort
    u64*    sel  = (u64*)(ws + OFF_SEL);
    float4* boxes = (float4*)(ws + OFF_BOX);
    int*    cls  = (int*)(ws + OFF_CLS);
    u64*    rinit = (u64*)(ws + OFF_RINIT);
    int*    keep = (int*)(ws + OFF_KEEP);

    hipMemsetAsync(ws + OFF_HIST, 0, ZERO_BYTES, stream);

    k_score<<<SC2_BLOCKS, 128, 0, stream>>>(clean, patch, keys);
    k_hist<<<dim3(NIMG, 16), 256, 0, stream>>>(keys, hist);
    k_thresh<<<NIMG, 1024, 0, stream>>>(hist, tbin);
    k_compact<<<dim3(NIMG, 16), 256, 0, stream>>>(keys, tbin, ccnt, cand);
    k_sort<<<NIMG, 1024, 0, stream>>>(cand, ccnt, sel);
    k_gather<<<NIMG, 1024, 0, stream>>>(clean, patch, sel, boxes, cls, rinit);
    k_nms_mask<<<dim3(NIMG, 16), 1024, 0, stream>>>(boxes, cls, mask, diag);
    k_nms_scan<<<NIMG, 1024, KMAX * 16 * 8 + KMAX * 8, stream>>>(mask, diag, rinit, keep);
    k_match_partial<<<dim3(8, 16), 256, 0, stream>>>(boxes, cls, keep, pmax);
    k_match_reduce<<<8, 256, 0, stream>>>(pmax, keep, sums, cnts);
    k_final<<<1, 64, 0, stream>>>(sums, cnts, out);
}